// Round 17
// baseline (359.650 us; speedup 1.0000x reference)
//
#include <hip/hip_runtime.h>
#include <hip/hip_bf16.h>

#define TN 131072      // total nodes (B*N)
#define NB 256         // batches
#define NN 512         // nodes per batch
#define FD 128         // per-layer feature dim
#define DD 512         // concat dim
#define NE 2097152     // edges
#define NEB 8192       // edges per batch (NN*DEG)
#define NL 4           // layers
#define PITCH 136      // LDS row pitch in bf16 units (272 B)
#define CHK 32         // dst nodes per chunk (double-buffered agg)
#define NCH 16         // chunks per batch
#define CICAP 832      // staged edge-offsets per chunk (exp 544, +12 sigma)

typedef __attribute__((ext_vector_type(8))) short bf16x8;
typedef __attribute__((ext_vector_type(4))) float f32x4;

__device__ __forceinline__ float b2f(unsigned int u) {
    union { unsigned int i; float f; } c; c.i = u << 16; return c.f;
}
__device__ __forceinline__ unsigned short f2b(float f) {
    union { float f; unsigned int i; } c; c.f = f;
    unsigned int x = c.i;
    return (unsigned short)((x + 0x7fffu + ((x >> 16) & 1u)) >> 16);  // RNE
}
__device__ __forceinline__ void add2(float& a0, float& a1, unsigned int v) {
    union { unsigned int u; float f; } lo, hi;
    lo.u = v << 16; hi.u = v & 0xffff0000u;
    a0 += lo.f; a1 += hi.f;
}
__device__ __forceinline__ void set2(float& a0, float& a1, unsigned int v) {
    union { unsigned int u; float f; } lo, hi;
    lo.u = v << 16; hi.u = v & 0xffff0000u;
    a0 = lo.f; a1 = hi.f;
}
__device__ __forceinline__ uint4 packv8(const float* a) {
    uint4 p;
    p.x = (unsigned int)f2b(a[0]) | ((unsigned int)f2b(a[1]) << 16);
    p.y = (unsigned int)f2b(a[2]) | ((unsigned int)f2b(a[3]) << 16);
    p.z = (unsigned int)f2b(a[4]) | ((unsigned int)f2b(a[5]) << 16);
    p.w = (unsigned int)f2b(a[6]) | ((unsigned int)f2b(a[7]) << 16);
    return p;
}
// fast tanh: (e^{2x}-1)/(e^{2x}+1), clamped (bf16-exact saturation)
__device__ __forceinline__ float ftanh(float x) {
    float xc = fminf(fmaxf(x, -9.0f), 9.0f);
    float e = __expf(2.0f * xc);
    return (e - 1.0f) * __builtin_amdgcn_rcpf(e + 1.0f);
}
// async global->LDS, 16B per lane
__device__ __forceinline__ void gl_lds16(const unsigned short* g, unsigned short* l) {
    __builtin_amdgcn_global_load_lds(
        (const __attribute__((address_space(1))) unsigned int*)g,
        (__attribute__((address_space(3))) unsigned int*)l,
        16, 0, 0);
}
// acc += p.lo(bf16) * q.lo(bf16) + p.hi * q.hi  (fp32 accumulate)
__device__ __forceinline__ void dot2acc(float& acc, unsigned int p, unsigned int ones) {
    asm("v_dot2_f32_bf16 %0, %1, %2, %0" : "+v"(acc) : "v"(p), "v"(ones));
}

// ---------------- fused per-batch CSR build (LDS atomics) ----------------
__global__ __launch_bounds__(1024) void csr_b_k(
    const int* __restrict__ src, const int* __restrict__ dst,
    int* __restrict__ row_ptr, int* __restrict__ col_off,
    float* __restrict__ degs)
{
    __shared__ int cnt[NN];     // counts, then reused as cursor
    __shared__ int ss[NN];      // scan ladder
    int b = blockIdx.x, t = threadIdx.x;
    int e0 = b * NEB;
    if (t < NN) cnt[t] = 0;
    __syncthreads();
    #pragma unroll
    for (int i = 0; i < NEB / 1024; i++) {
        int d = dst[e0 + t + i * 1024] & (NN - 1);
        atomicAdd(&cnt[d], 1);
    }
    __syncthreads();
    int c = 0;
    if (t < NN) { c = cnt[t]; ss[t] = c; }
    __syncthreads();
    for (int off = 1; off < NN; off <<= 1) {
        int v = (t < NN && t >= off) ? ss[t - off] : 0;
        __syncthreads();
        if (t < NN) ss[t] += v;
        __syncthreads();
    }
    if (t < NN) {
        int excl = ss[t] - c;
        int gid = b * NN + t;
        row_ptr[gid] = e0 + excl;
        degs[gid] = (float)(c + 1);
        cnt[t] = excl;          // cursor (batch-relative)
        if (b == NB - 1 && t == NN - 1) row_ptr[TN] = NE;
    }
    __syncthreads();
    #pragma unroll
    for (int i = 0; i < NEB / 1024; i++) {
        int e = e0 + t + i * 1024;
        int d = dst[e] & (NN - 1);
        int p = atomicAdd(&cnt[d], 1);
        col_off[e0 + p] = (src[e] & (NN - 1)) * (PITCH * 2);
    }
}

// ---------------- att_W transpose + bf16 cast:  Wt[n][k] = bf16(W[k][n]) ----------------
__global__ __launch_bounds__(256) void transpose_cast_k(const float* __restrict__ W,
                                                        unsigned short* __restrict__ Wt) {
    __shared__ float tile[32][33];
    int k0 = blockIdx.x * 32, n0 = blockIdx.y * 32;
    int tx = threadIdx.x & 31, ty = threadIdx.x >> 5;  // 32 x 8
    #pragma unroll
    for (int i = 0; i < 32; i += 8)
        tile[ty + i][tx] = W[(size_t)(k0 + ty + i) * DD + n0 + tx];
    __syncthreads();
    #pragma unroll
    for (int i = 0; i < 32; i += 8)
        Wt[(size_t)(n0 + ty + i) * DD + k0 + tx] = f2b(tile[tx][ty + i]);
}

// ---------------- conv_W transpose + bf16 cast per layer: Wt_l[o][f] = bf16(W_l[f][o]) ----
__global__ __launch_bounds__(256) void transp_convW_k(const float* __restrict__ W,
                                                      unsigned short* __restrict__ Wt) {
    __shared__ float tile[32][33];
    const float* Wl = W + (size_t)blockIdx.z * FD * FD;
    unsigned short* Wtl = Wt + (size_t)blockIdx.z * FD * FD;
    int f0 = blockIdx.x * 32, o0 = blockIdx.y * 32;
    int tx = threadIdx.x & 31, ty = threadIdx.x >> 5;
    #pragma unroll
    for (int i = 0; i < 32; i += 8)
        tile[ty + i][tx] = Wl[(size_t)(f0 + ty + i) * FD + o0 + tx];
    __syncthreads();
    #pragma unroll
    for (int i = 0; i < 32; i += 8)
        Wtl[(size_t)(o0 + ty + i) * FD + f0 + tx] = f2b(tile[tx][ty + i]);
}

// ---------------- fused all-layer conv v10: v7 structure + perm/dot2 gather ----------------
__global__ __launch_bounds__(1024) void conv_all_k(
    const float* __restrict__ node_feat,      // [TN][FD] fp32
    const unsigned short* __restrict__ Wt,    // [NL*FD][FD] bf16 (out,f)
    const float* __restrict__ bias,           // [NL*FD]
    const int* __restrict__ rp, const int* __restrict__ coff,
    const float* __restrict__ degs,
    unsigned short* __restrict__ cat)         // [TN][DD] bf16
{
    __shared__ unsigned short hW[NN * PITCH];        // 139,264 B
    __shared__ unsigned short agg[2][CHK * PITCH];   // 17,408 B
    __shared__ int ciL[2][CICAP];                    // 6,656 B
    const int tid = threadIdx.x;
    const int g0 = blockIdx.x * NN;
    const int lane = tid & 63, w = tid >> 6;
    const int lr = lane & 15, lh = lane >> 4;
    const int mo = w >> 1, nd = w & 1;     // mfma: 8(out-tiles) x 2(dst-tiles)
    const int gn = tid >> 5;               // gather: node in chunk (0..31)
    const int gs = tid & 31;               // gather: 8B unit (4 feats) in row
    const char* hWb = (const char*)hW;
    const unsigned int SEL0 = 0x01000504u; // (a.f0, b.f0)
    const unsigned int SEL1 = 0x03020706u; // (a.f1, b.f1)
    const unsigned int ONES = 0x3F803F80u; // bf16 (1.0, 1.0)

    // initial stage: node_feat fp32 -> hW bf16
    #pragma unroll
    for (int i = 0; i < 8; i++) {
        int u = tid + i * 1024;
        int row = u >> 4, cu = u & 15;
        const float4* s4 = (const float4*)(node_feat + (size_t)(g0 + row) * FD + cu * 8);
        float4 x = s4[0], y = s4[1];
        float tmp[8] = {x.x, x.y, x.z, x.w, y.x, y.y, y.z, y.w};
        *(uint4*)&hW[row * PITCH + cu * 8] = packv8(tmp);
    }
    __syncthreads();

    // gather one node's aggregation (32 lanes/node, offsets from LDS)
    auto do_gather = [&](int nl, int rs, int re, int eb, const int* cib,
                         unsigned short* buf) {
        const char* rowb = hWb + nl * (PITCH * 2);
        uint2 v = *(const uint2*)(rowb + gs * 8);
        float a0, a1, a2, a3;
        set2(a0, a1, v.x); set2(a2, a3, v.y);
        int r1 = re;
        int rlim = eb + CICAP; if (r1 > rlim) r1 = rlim;
        int j = rs;
        for (; j + 8 <= r1; j += 8) {
            int off[8];
            #pragma unroll
            for (int i = 0; i < 8; i++) off[i] = cib[j - eb + i];
            uint2 u[8];
            #pragma unroll
            for (int i = 0; i < 8; i++) u[i] = *(const uint2*)(hWb + off[i] + gs * 8);
            #pragma unroll
            for (int i = 0; i < 4; i++) {
                unsigned int x1 = u[2 * i].x, x2 = u[2 * i + 1].x;
                unsigned int y1 = u[2 * i].y, y2 = u[2 * i + 1].y;
                dot2acc(a0, __builtin_amdgcn_perm(x1, x2, SEL0), ONES);
                dot2acc(a1, __builtin_amdgcn_perm(x1, x2, SEL1), ONES);
                dot2acc(a2, __builtin_amdgcn_perm(y1, y2, SEL0), ONES);
                dot2acc(a3, __builtin_amdgcn_perm(y1, y2, SEL1), ONES);
            }
        }
        for (; j + 2 <= r1; j += 2) {
            int o0 = cib[j - eb], o1 = cib[j - eb + 1];
            uint2 u0 = *(const uint2*)(hWb + o0 + gs * 8);
            uint2 u1 = *(const uint2*)(hWb + o1 + gs * 8);
            dot2acc(a0, __builtin_amdgcn_perm(u0.x, u1.x, SEL0), ONES);
            dot2acc(a1, __builtin_amdgcn_perm(u0.x, u1.x, SEL1), ONES);
            dot2acc(a2, __builtin_amdgcn_perm(u0.y, u1.y, SEL0), ONES);
            dot2acc(a3, __builtin_amdgcn_perm(u0.y, u1.y, SEL1), ONES);
        }
        if (j < r1) {
            int off = cib[j - eb];
            uint2 u = *(const uint2*)(hWb + off + gs * 8);
            add2(a0, a1, u.x); add2(a2, a3, u.y);
            j = r1;
        }
        for (; j < re; j++) {      // rare overflow tail: offsets from global
            int off = coff[j];
            uint2 u = *(const uint2*)(hWb + off + gs * 8);
            add2(a0, a1, u.x); add2(a2, a3, u.y);
        }
        uint2 pk;
        pk.x = (unsigned int)f2b(a0) | ((unsigned int)f2b(a1) << 16);
        pk.y = (unsigned int)f2b(a2) | ((unsigned int)f2b(a3) << 16);
        *(uint2*)&buf[gn * PITCH + gs * 4] = pk;
    };

    for (int l = 0; l < NL; l++) {
        // Wt fragments (A operand, m=out) + bias in regs for the whole layer
        bf16x8 af[4];
        #pragma unroll
        for (int ks = 0; ks < 4; ks++)
            af[ks] = *(const bf16x8*)&Wt[((size_t)l * FD + mo * 16 + lr) * FD + ks * 32 + lh * 8];
        float4 bs = *(const float4*)&bias[l * FD + mo * 16 + lh * 4];

        // prologue: stage ciL[0], ciL[1]; gather chunk 0
        {
            int eb0 = rp[g0];
            int cnt0 = rp[g0 + CHK] - eb0;      if (cnt0 > CICAP) cnt0 = CICAP;
            int eb1 = rp[g0 + CHK];
            int cnt1 = rp[g0 + 2 * CHK] - eb1;  if (cnt1 > CICAP) cnt1 = CICAP;
            int rs0 = rp[g0 + gn], re0 = rp[g0 + gn + 1];
            if (tid < cnt0) ciL[0][tid] = coff[eb0 + tid];
            if (tid < cnt1) ciL[1][tid] = coff[eb1 + tid];
            __syncthreads();
            do_gather(gn, rs0, re0, eb0, ciL[0], agg[0]);
        }
        __syncthreads();

        for (int c = 0; c < NCH; c++) {
            int cur = c & 1;
            // prefetch next-gather bounds (issued early, consumed after MFMA)
            int rs_n = 0, re_n = 0, eb_n = 0;
            if (c < NCH - 1) {
                eb_n = rp[g0 + (c + 1) * CHK];
                rs_n = rp[g0 + (c + 1) * CHK + gn];
                re_n = rp[g0 + (c + 1) * CHK + gn + 1];
            }
            // stage-load offsets for chunk c+2 (committed to LDS after epilogue)
            int scnt = 0, sval = 0;
            if (c <= NCH - 3) {
                int eb2 = rp[g0 + (c + 2) * CHK];
                scnt = rp[g0 + (c + 3) * CHK] - eb2; if (scnt > CICAP) scnt = CICAP;
                if (tid < scnt) sval = coff[eb2 + tid];
            }
            // ---- MFMA(c): m=out 128, n=dst 32, k=f 128 ----
            f32x4 cc = (f32x4){0.f, 0.f, 0.f, 0.f};
            {
                const unsigned short* ab = &agg[cur][(nd * 16 + lr) * PITCH + lh * 8];
                #pragma unroll
                for (int ks = 0; ks < 4; ks++) {
                    bf16x8 bfv = *(const bf16x8*)&ab[ks * 32];
                    cc = __builtin_amdgcn_mfma_f32_16x16x32_bf16(af[ks], bfv, cc, 0, 0, 0);
                }
            }
            // ---- epilogue: tanh((lin+b)*rdeg) -> cat (8B packed stores) ----
            {
                int dstl = c * CHK + nd * 16 + lr;
                float rd = __builtin_amdgcn_rcpf(degs[g0 + dstl]);
                float t0 = ftanh((cc[0] + bs.x) * rd);
                float t1 = ftanh((cc[1] + bs.y) * rd);
                float t2 = ftanh((cc[2] + bs.z) * rd);
                float t3 = ftanh((cc[3] + bs.w) * rd);
                uint2 pk;
                pk.x = (unsigned int)f2b(t0) | ((unsigned int)f2b(t1) << 16);
                pk.y = (unsigned int)f2b(t2) | ((unsigned int)f2b(t3) << 16);
                *(uint2*)&cat[(size_t)(g0 + dstl) * DD + l * FD + mo * 16 + lh * 4] = pk;
            }
            // commit staged offsets for c+2 into ciL[(c+2)&1] == ciL[cur]
            if (tid < scnt) ciL[cur][tid] = sval;
            // ---- gather(c+1) into the other agg buffer ----
            if (c < NCH - 1)
                do_gather((c + 1) * CHK + gn, rs_n, re_n, eb_n, ciL[(c + 1) & 1], agg[cur ^ 1]);
            __syncthreads();
        }

        // restage hW from this layer's output (L2-hot cat)
        if (l < NL - 1) {
            #pragma unroll
            for (int i = 0; i < 8; i++) {
                int u = tid + i * 1024;
                int row = u >> 4, cu = u & 15;
                uint4 v = *(const uint4*)&cat[(size_t)(g0 + row) * DD + l * FD + cu * 8];
                *(uint4*)&hW[row * PITCH + cu * 8] = v;
            }
            __syncthreads();
        }
    }
}

// ---------------- attention scores v4: full-X panel in LDS, n-fused ----------------
// Grid 1024 (m-panels of 128 rows), 512 threads (8 waves, 2m x 4n). X panel
// [128][512] bf16 staged ONCE (128KB, swizzled 16B units); Wt consumed as 32KB
// 64-k chunks of 256 cols (L2-resident). 2 n-passes x 8 k-chunks, 2 barriers per
// chunk. Epilogue accumulates per-row partials across passes; sp = [TN][4].
__global__ __launch_bounds__(512) void scores_k(
    const unsigned short* __restrict__ X,   // [TN][DD] bf16
    const unsigned short* __restrict__ Wt,  // [DD][DD] bf16, (n,k)
    const float* __restrict__ bv, const float* __restrict__ vv,
    float* __restrict__ sp)                 // [TN][4] partials
{
    __shared__ unsigned short sXl[128 * 512];   // 131,072 B
    __shared__ unsigned short sWc[256 * 64];    //  32,768 B
    int bid = blockIdx.x;
    int swz = (bid & 7) * 128 + (bid >> 3);     // 1024 blocks, 8 XCDs
    int m0 = swz * 128;
    int tid = threadIdx.x;
    int lane = tid & 63, w = tid >> 6;
    int wm = w >> 2, wn = w & 3;                // 2(m) x 4(n)
    int lr = lane & 15, lh = lane >> 4;

    // stage full X panel: 8192 16B units, pre-swizzled source
    #pragma unroll
    for (int i = 0; i < 16; i++) {
        int u = tid + i * 512;
        int row = u >> 6, ul = u & 63;
        int su = ul ^ (row & 7);
        gl_lds16(&X[(size_t)(m0 + row) * DD + su * 8], &sXl[u * 8]);
    }

    float part[4][4];   // [mi][r], accumulated across both n-passes
    #pragma unroll
    for (int mi = 0; mi < 4; mi++)
        #pragma unroll
        for (int r = 0; r < 4; r++) part[mi][r] = 0.f;

    #pragma unroll
    for (int p = 0; p < 2; p++) {
        int n0 = p * 256;
        f32x4 acc[4][4];
        #pragma unroll
        for (int mi = 0; mi < 4; mi++)
            #pragma unroll
            for (int ni = 0; ni < 4; ni++)
                acc[mi][ni] = (f32x4){0.f, 0.f, 0.f, 0.f};

        for (int kc = 0; kc < 8; kc++) {
            __syncthreads();   // prev chunk reads done (also drains X-stage, 1st iter)
            #pragma unroll
            for (int i = 0; i < 4; i++) {
                int u = tid + i * 512;
                int row = u >> 3, ul = u & 7;
                int su = ul ^ (row & 7);
                gl_lds16(&Wt[(size_t)(n0 + row) * DD + kc * 64 + su * 8], &sWc[u * 8]);
            }
            __syncthreads();   // sWc ready
            #pragma unroll
            for (int kk = 0; kk < 2; kk++) {
                bf16x8 afv[4], bfv[4];
                #pragma unroll
                for (int mi = 0; mi < 4; mi++) {
                    int rr = wm * 64 + mi * 16 + lr;
                    int ulog = kc * 8 + kk * 4 + lh;
                    afv[mi] = *(const bf16x8*)&sXl[rr * 512 + ((ulog ^ (rr & 7)) << 3)];
                }
                #pragma unroll
                for (int ni = 0; ni < 4; ni++) {
                    int rn = wn * 64 + ni * 16 + lr;
                    int ulog = kk * 4 + lh;
                    bfv[ni] = *(const bf16x8*)&sWc[rn * 64 + ((ulog ^ (rn & 7)) << 3)];
                }
                #pragma unroll
                for (int mi = 0; mi < 4; mi++)
                    #pragma unroll
                    for (int ni = 0; ni < 4; ni++)
                        acc[mi][ni] = __builtin_amdgcn_mfma_f32_16x16x32_bf16(
                            afv[mi], bfv[ni], acc[mi][ni], 0, 0, 0);
            }
        }

        // fold this pass into per-row partials
        float vcol[4], bcol[4];
        #pragma unroll
        for (int ni = 0; ni < 4; ni++) {
            int col = n0 + wn * 64 + ni * 16 + lr;
            vcol[ni] = vv[col];
            bcol[ni] = bv[col];
        }
        #pragma unroll
        for (int mi = 0; mi < 4; mi++)
            #pragma unroll
            for (int r = 0; r < 4; r++) {
                float s = 0.f;
                #pragma unroll
                for (int ni = 0; ni < 4; ni++)
                    s += ftanh(acc[mi][ni][r] + bcol[ni]) * vcol[ni];
                part[mi][r] += s;
            }
    }

    // reduce over lr (16 lanes) and write one partial per (row, wn)
    #pragma unroll
    for (int mi = 0; mi < 4; mi++) {
        #pragma unroll
        for (int r = 0; r < 4; r++) {
            float s = part[mi][r];
            s += __shfl_xor(s, 1);
            s += __shfl_xor(s, 2);
            s += __shfl_xor(s, 4);
            s += __shfl_xor(s, 8);
            if (lr == 0) {
                int row = m0 + wm * 64 + mi * 16 + lh * 4 + r;
                sp[(size_t)row * 4 + wn] = s;
            }
        }
    }
}

// ---------------- softmax + pool v3b: 4 row-groups x 128 cols, float4 score read ----
__global__ __launch_bounds__(512) void pool_k(
    const float* __restrict__ sp, const unsigned short* __restrict__ X,
    float* __restrict__ pooled)
{
    __shared__ float sattn[512];
    __shared__ float wmax[8];
    __shared__ float wsum[8];
    __shared__ float pred[3][512];
    int b = blockIdx.x, t = threadIdx.x;
    int lane = t & 63, wid = t >> 6;

    float s;
    {
        float4 x = *(const float4*)&sp[((size_t)b * NN + t) * 4];
        s = x.x + x.y + x.z + x.w;
    }
    float m = s;
    #pragma unroll
    for (int off = 1; off < 64; off <<= 1) m = fmaxf(m, __shfl_xor(m, off));
    if (lane == 0) wmax[wid] = m;
    __syncthreads();
    m = wmax[0];
    #pragma unroll
    for (int i = 1; i < 8; i++) m = fmaxf(m, wmax[i]);
    float e = expf(s - m);
    float ssum = e;
    #pragma unroll
    for (int off = 1; off < 64; off <<= 1) ssum += __shfl_xor(ssum, off);
    if (lane == 0) wsum[wid] = ssum;
    __syncthreads();
    float tot = wsum[0];
    #pragma unroll
    for (int i = 1; i < 8; i++) tot += wsum[i];
    sattn[t] = e * (1.0f / tot);
    __syncthreads();

    // pooling: 4 row-groups of 128; thread tc owns feats [4tc..4tc+3]
    int rg = t >> 7, tc = t & 127;
    float4 acc = {0.f, 0.f, 0.f, 0.f};
    const unsigned short* Xb = X + (size_t)b * NN * DD;
    int n0 = rg * 128;
    #pragma unroll 4
    for (int n = n0; n < n0 + 128; n++) {
        float a = sattn[n];
        uint2 px = *(const uint2*)&Xb[(size_t)n * DD + tc * 4];
        acc.x += a * b2f(px.x & 0xffff);
        acc.y += a * b2f(px.x >> 16);
        acc.z += a * b2f(px.y & 0xffff);
        acc.w += a * b2f(px.y >> 16);
    }
    if (rg > 0) *(float4*)&pred[rg - 1][tc * 4] = acc;
    __syncthreads();
    if (rg == 0) {
        #pragma unroll
        for (int g = 0; g < 3; g++) {
            float4 q = *(const float4*)&pred[g][tc * 4];
            acc.x += q.x; acc.y += q.y; acc.z += q.z; acc.w += q.w;
        }
        *(float4*)&pooled[b * DD + tc * 4] = acc;
    }
}

// ---------------- output layer ----------------
__global__ void out_k(const float* __restrict__ pooled, const float* __restrict__ Wo,
                      const float* __restrict__ bo, float* __restrict__ out) {
    int b = blockIdx.x, c = threadIdx.x;  // 128 threads
    float acc = 0.f;
    const float* p = pooled + b * DD;
    for (int k = 0; k < DD; k++) acc += p[k] * Wo[k * 128 + c];
    out[b * 128 + c] = fmaxf(acc + bo[c], 0.f);
}

extern "C" void kernel_launch(void* const* d_in, const int* in_sizes, int n_in,
                              void* d_out, int out_size, void* d_ws, size_t ws_size,
                              hipStream_t stream)
{
    const float* node_feat = (const float*)d_in[0];
    const int*   edge_src  = (const int*)d_in[1];
    const int*   edge_dst  = (const int*)d_in[2];
    const float* conv_W    = (const float*)d_in[3];
    const float* conv_b    = (const float*)d_in[4];
    const float* att_W     = (const float*)d_in[5];
    const float* att_b     = (const float*)d_in[6];
    const float* att_v     = (const float*)d_in[7];
    const float* out_W     = (const float*)d_in[8];
    const float* out_b     = (const float*)d_in[9];
    float* out = (float*)d_out;
    (void)in_sizes; (void)n_in; (void)out_size;

    char* ws = (char*)d_ws;
    size_t off = 0;
    auto alloc = [&](size_t bytes) {
        void* p = ws + off;
        off += (bytes + 255) & ~(size_t)255;
        return p;
    };
    unsigned short* cat   = (unsigned short*)alloc((size_t)TN * DD * 2);  // bf16
    int*   row_ptr = (int*)alloc((size_t)(TN + 1) * 4);
    int*   col_off = (int*)alloc((size_t)NE * 4);
    float* degs    = (float*)alloc((size_t)TN * 4);
    float* sp      = (float*)alloc((size_t)TN * 4 * 4);
    unsigned short* attWt = (unsigned short*)alloc((size_t)DD * DD * 2);  // bf16
    unsigned short* convWt = (unsigned short*)alloc((size_t)NL * FD * FD * 2);
    float* pooled  = (float*)alloc((size_t)NB * DD * 4);
    if (off > ws_size) return;  // diagnostic guard

    csr_b_k<<<NB, 1024, 0, stream>>>(edge_src, edge_dst, row_ptr, col_off, degs);
    transpose_cast_k<<<dim3(DD / 32, DD / 32), 256, 0, stream>>>(att_W, attWt);
    transp_convW_k<<<dim3(FD / 32, FD / 32, NL), 256, 0, stream>>>(conv_W, convWt);

    conv_all_k<<<NB, 1024, 0, stream>>>(node_feat, convWt, conv_b,
                                        row_ptr, col_off, degs, cat);

    scores_k<<<1024, 512, 0, stream>>>(cat, attWt, att_b, att_v, sp);
    pool_k<<<NB, 512, 0, stream>>>(sp, cat, pooled);
    out_k<<<NB, 128, 0, stream>>>(pooled, out_W, out_b, out);
}

// Round 18
// 354.555 us; speedup vs baseline: 1.0144x; 1.0144x over previous
//
#include <hip/hip_runtime.h>
#include <hip/hip_bf16.h>

#define TN 131072      // total nodes (B*N)
#define NB 256         // batches
#define NN 512         // nodes per batch
#define FD 128         // per-layer feature dim
#define DD 512         // concat dim
#define NE 2097152     // edges
#define NEB 8192       // edges per batch (NN*DEG)
#define NL 4           // layers
#define PITCH 136      // LDS row pitch in bf16 units (272 B)
#define CHK 32         // dst nodes per chunk (double-buffered agg)
#define NCH 16         // chunks per batch
#define CICAP 576      // staged edge-offsets per chunk (exp 512, +2.8 sigma; overflow->global tail)

typedef __attribute__((ext_vector_type(8))) short bf16x8;
typedef __attribute__((ext_vector_type(4))) float f32x4;

__device__ __forceinline__ float b2f(unsigned int u) {
    union { unsigned int i; float f; } c; c.i = u << 16; return c.f;
}
__device__ __forceinline__ unsigned short f2b(float f) {
    union { float f; unsigned int i; } c; c.f = f;
    unsigned int x = c.i;
    return (unsigned short)((x + 0x7fffu + ((x >> 16) & 1u)) >> 16);  // RNE
}
__device__ __forceinline__ void add2(float& a0, float& a1, unsigned int v) {
    union { unsigned int u; float f; } lo, hi;
    lo.u = v << 16; hi.u = v & 0xffff0000u;
    a0 += lo.f; a1 += hi.f;
}
__device__ __forceinline__ void set2(float& a0, float& a1, unsigned int v) {
    union { unsigned int u; float f; } lo, hi;
    lo.u = v << 16; hi.u = v & 0xffff0000u;
    a0 = lo.f; a1 = hi.f;
}
__device__ __forceinline__ uint4 packv8(const float* a) {
    uint4 p;
    p.x = (unsigned int)f2b(a[0]) | ((unsigned int)f2b(a[1]) << 16);
    p.y = (unsigned int)f2b(a[2]) | ((unsigned int)f2b(a[3]) << 16);
    p.z = (unsigned int)f2b(a[4]) | ((unsigned int)f2b(a[5]) << 16);
    p.w = (unsigned int)f2b(a[6]) | ((unsigned int)f2b(a[7]) << 16);
    return p;
}
// fast tanh: (e^{2x}-1)/(e^{2x}+1), clamped (bf16-exact saturation)
__device__ __forceinline__ float ftanh(float x) {
    float xc = fminf(fmaxf(x, -9.0f), 9.0f);
    float e = __expf(2.0f * xc);
    return (e - 1.0f) * __builtin_amdgcn_rcpf(e + 1.0f);
}
// async global->LDS, 16B per lane
__device__ __forceinline__ void gl_lds16(const unsigned short* g, unsigned short* l) {
    __builtin_amdgcn_global_load_lds(
        (const __attribute__((address_space(1))) unsigned int*)g,
        (__attribute__((address_space(3))) unsigned int*)l,
        16, 0, 0);
}
// acc += p.lo(bf16) * q.lo(bf16) + p.hi * q.hi  (fp32 accumulate)
__device__ __forceinline__ void dot2acc(float& acc, unsigned int p, unsigned int ones) {
    asm("v_dot2_f32_bf16 %0, %1, %2, %0" : "+v"(acc) : "v"(p), "v"(ones));
}

// ---------------- fused per-batch CSR build (LDS atomics) ----------------
__global__ __launch_bounds__(1024) void csr_b_k(
    const int* __restrict__ src, const int* __restrict__ dst,
    int* __restrict__ row_ptr, int* __restrict__ col_off,
    float* __restrict__ degs)
{
    __shared__ int cnt[NN];     // counts, then reused as cursor
    __shared__ int ss[NN];      // scan ladder
    int b = blockIdx.x, t = threadIdx.x;
    int e0 = b * NEB;
    if (t < NN) cnt[t] = 0;
    __syncthreads();
    #pragma unroll
    for (int i = 0; i < NEB / 1024; i++) {
        int d = dst[e0 + t + i * 1024] & (NN - 1);
        atomicAdd(&cnt[d], 1);
    }
    __syncthreads();
    int c = 0;
    if (t < NN) { c = cnt[t]; ss[t] = c; }
    __syncthreads();
    for (int off = 1; off < NN; off <<= 1) {
        int v = (t < NN && t >= off) ? ss[t - off] : 0;
        __syncthreads();
        if (t < NN) ss[t] += v;
        __syncthreads();
    }
    if (t < NN) {
        int excl = ss[t] - c;
        int gid = b * NN + t;
        row_ptr[gid] = e0 + excl;
        degs[gid] = (float)(c + 1);
        cnt[t] = excl;          // cursor (batch-relative)
        if (b == NB - 1 && t == NN - 1) row_ptr[TN] = NE;
    }
    __syncthreads();
    #pragma unroll
    for (int i = 0; i < NEB / 1024; i++) {
        int e = e0 + t + i * 1024;
        int d = dst[e] & (NN - 1);
        int p = atomicAdd(&cnt[d], 1);
        col_off[e0 + p] = (src[e] & (NN - 1)) * (PITCH * 2);
    }
}

// ---------------- merged prep: attW transpose (z=0) + conv_W transpose (z=1..4) --------
__global__ __launch_bounds__(256) void prep_k(const float* __restrict__ attW,
                                              const float* __restrict__ convW,
                                              unsigned short* __restrict__ attWt,
                                              unsigned short* __restrict__ convWt) {
    __shared__ float tile[32][33];
    int z = blockIdx.z;
    int tx = threadIdx.x & 31, ty = threadIdx.x >> 5;  // 32 x 8
    if (z == 0) {
        int k0 = blockIdx.x * 32, n0 = blockIdx.y * 32;
        #pragma unroll
        for (int i = 0; i < 32; i += 8)
            tile[ty + i][tx] = attW[(size_t)(k0 + ty + i) * DD + n0 + tx];
        __syncthreads();
        #pragma unroll
        for (int i = 0; i < 32; i += 8)
            attWt[(size_t)(n0 + ty + i) * DD + k0 + tx] = f2b(tile[tx][ty + i]);
    } else {
        if (blockIdx.x >= FD / 32 || blockIdx.y >= FD / 32) return;
        const float* Wl = convW + (size_t)(z - 1) * FD * FD;
        unsigned short* Wtl = convWt + (size_t)(z - 1) * FD * FD;
        int f0 = blockIdx.x * 32, o0 = blockIdx.y * 32;
        #pragma unroll
        for (int i = 0; i < 32; i += 8)
            tile[ty + i][tx] = Wl[(size_t)(f0 + ty + i) * FD + o0 + tx];
        __syncthreads();
        #pragma unroll
        for (int i = 0; i < 32; i += 8)
            Wtl[(size_t)(o0 + ty + i) * FD + f0 + tx] = f2b(tile[tx][ty + i]);
    }
}

// ---------------- fused all-layer conv v11: v10 + rp staged in LDS ----------------
__global__ __launch_bounds__(1024) void conv_all_k(
    const float* __restrict__ node_feat,      // [TN][FD] fp32
    const unsigned short* __restrict__ Wt,    // [NL*FD][FD] bf16 (out,f)
    const float* __restrict__ bias,           // [NL*FD]
    const int* __restrict__ rp, const int* __restrict__ coff,
    const float* __restrict__ degs,
    unsigned short* __restrict__ cat)         // [TN][DD] bf16
{
    __shared__ unsigned short hW[NN * PITCH];        // 139,264 B
    __shared__ unsigned short agg[2][CHK * PITCH];   // 17,408 B
    __shared__ int ciL[2][CICAP];                    // 4,608 B
    __shared__ int rpL[NN + 1];                      // 2,052 B  (total 163,332 <= 160 KiB)
    const int tid = threadIdx.x;
    const int g0 = blockIdx.x * NN;
    const int lane = tid & 63, w = tid >> 6;
    const int lr = lane & 15, lh = lane >> 4;
    const int mo = w >> 1, nd = w & 1;     // mfma: 8(out-tiles) x 2(dst-tiles)
    const int gn = tid >> 5;               // gather: node in chunk (0..31)
    const int gs = tid & 31;               // gather: 8B unit (4 feats) in row
    const char* hWb = (const char*)hW;
    const unsigned int SEL0 = 0x01000504u; // (a.f0, b.f0)
    const unsigned int SEL1 = 0x03020706u; // (a.f1, b.f1)
    const unsigned int ONES = 0x3F803F80u; // bf16 (1.0, 1.0)

    // stage rp window (batch-relative index, global edge values)
    if (tid <= NN) rpL[tid] = rp[g0 + tid];

    // initial stage: node_feat fp32 -> hW bf16
    #pragma unroll
    for (int i = 0; i < 8; i++) {
        int u = tid + i * 1024;
        int row = u >> 4, cu = u & 15;
        const float4* s4 = (const float4*)(node_feat + (size_t)(g0 + row) * FD + cu * 8);
        float4 x = s4[0], y = s4[1];
        float tmp[8] = {x.x, x.y, x.z, x.w, y.x, y.y, y.z, y.w};
        *(uint4*)&hW[row * PITCH + cu * 8] = packv8(tmp);
    }
    __syncthreads();

    // gather one node's aggregation (32 lanes/node, offsets from LDS)
    auto do_gather = [&](int nl, int rs, int re, int eb, const int* cib,
                         unsigned short* buf) {
        const char* rowb = hWb + nl * (PITCH * 2);
        uint2 v = *(const uint2*)(rowb + gs * 8);
        float a0, a1, a2, a3;
        set2(a0, a1, v.x); set2(a2, a3, v.y);
        int r1 = re;
        int rlim = eb + CICAP; if (r1 > rlim) r1 = rlim;
        int j = rs;
        for (; j + 8 <= r1; j += 8) {
            int off[8];
            #pragma unroll
            for (int i = 0; i < 8; i++) off[i] = cib[j - eb + i];
            uint2 u[8];
            #pragma unroll
            for (int i = 0; i < 8; i++) u[i] = *(const uint2*)(hWb + off[i] + gs * 8);
            #pragma unroll
            for (int i = 0; i < 4; i++) {
                unsigned int x1 = u[2 * i].x, x2 = u[2 * i + 1].x;
                unsigned int y1 = u[2 * i].y, y2 = u[2 * i + 1].y;
                dot2acc(a0, __builtin_amdgcn_perm(x1, x2, SEL0), ONES);
                dot2acc(a1, __builtin_amdgcn_perm(x1, x2, SEL1), ONES);
                dot2acc(a2, __builtin_amdgcn_perm(y1, y2, SEL0), ONES);
                dot2acc(a3, __builtin_amdgcn_perm(y1, y2, SEL1), ONES);
            }
        }
        for (; j + 2 <= r1; j += 2) {
            int o0 = cib[j - eb], o1 = cib[j - eb + 1];
            uint2 u0 = *(const uint2*)(hWb + o0 + gs * 8);
            uint2 u1 = *(const uint2*)(hWb + o1 + gs * 8);
            dot2acc(a0, __builtin_amdgcn_perm(u0.x, u1.x, SEL0), ONES);
            dot2acc(a1, __builtin_amdgcn_perm(u0.x, u1.x, SEL1), ONES);
            dot2acc(a2, __builtin_amdgcn_perm(u0.y, u1.y, SEL0), ONES);
            dot2acc(a3, __builtin_amdgcn_perm(u0.y, u1.y, SEL1), ONES);
        }
        if (j < r1) {
            int off = cib[j - eb];
            uint2 u = *(const uint2*)(hWb + off + gs * 8);
            add2(a0, a1, u.x); add2(a2, a3, u.y);
            j = r1;
        }
        for (; j < re; j++) {      // rare overflow tail: offsets from global
            int off = coff[j];
            uint2 u = *(const uint2*)(hWb + off + gs * 8);
            add2(a0, a1, u.x); add2(a2, a3, u.y);
        }
        uint2 pk;
        pk.x = (unsigned int)f2b(a0) | ((unsigned int)f2b(a1) << 16);
        pk.y = (unsigned int)f2b(a2) | ((unsigned int)f2b(a3) << 16);
        *(uint2*)&buf[gn * PITCH + gs * 4] = pk;
    };

    for (int l = 0; l < NL; l++) {
        // Wt fragments (A operand, m=out) + bias in regs for the whole layer
        bf16x8 af[4];
        #pragma unroll
        for (int ks = 0; ks < 4; ks++)
            af[ks] = *(const bf16x8*)&Wt[((size_t)l * FD + mo * 16 + lr) * FD + ks * 32 + lh * 8];
        float4 bs = *(const float4*)&bias[l * FD + mo * 16 + lh * 4];

        // prologue: stage ciL[0], ciL[1]; gather chunk 0
        {
            int eb0 = rpL[0];
            int cnt0 = rpL[CHK] - eb0;          if (cnt0 > CICAP) cnt0 = CICAP;
            int eb1 = rpL[CHK];
            int cnt1 = rpL[2 * CHK] - eb1;      if (cnt1 > CICAP) cnt1 = CICAP;
            int rs0 = rpL[gn], re0 = rpL[gn + 1];
            if (tid < cnt0) ciL[0][tid] = coff[eb0 + tid];
            if (tid < cnt1) ciL[1][tid] = coff[eb1 + tid];
            __syncthreads();
            do_gather(gn, rs0, re0, eb0, ciL[0], agg[0]);
        }
        __syncthreads();

        for (int c = 0; c < NCH; c++) {
            int cur = c & 1;
            // prefetch next-gather bounds (LDS, cheap)
            int rs_n = 0, re_n = 0, eb_n = 0;
            if (c < NCH - 1) {
                eb_n = rpL[(c + 1) * CHK];
                rs_n = rpL[(c + 1) * CHK + gn];
                re_n = rpL[(c + 1) * CHK + gn + 1];
            }
            // stage-load offsets for chunk c+2 (committed to LDS after epilogue)
            int scnt = 0, sval = 0;
            if (c <= NCH - 3) {
                int eb2 = rpL[(c + 2) * CHK];
                scnt = rpL[(c + 3) * CHK] - eb2; if (scnt > CICAP) scnt = CICAP;
                if (tid < scnt) sval = coff[eb2 + tid];
            }
            // ---- MFMA(c): m=out 128, n=dst 32, k=f 128 ----
            f32x4 cc = (f32x4){0.f, 0.f, 0.f, 0.f};
            {
                const unsigned short* ab = &agg[cur][(nd * 16 + lr) * PITCH + lh * 8];
                #pragma unroll
                for (int ks = 0; ks < 4; ks++) {
                    bf16x8 bfv = *(const bf16x8*)&ab[ks * 32];
                    cc = __builtin_amdgcn_mfma_f32_16x16x32_bf16(af[ks], bfv, cc, 0, 0, 0);
                }
            }
            // ---- epilogue: tanh((lin+b)*rdeg) -> cat (8B packed stores) ----
            {
                int dstl = c * CHK + nd * 16 + lr;
                float rd = __builtin_amdgcn_rcpf(degs[g0 + dstl]);
                float t0 = ftanh((cc[0] + bs.x) * rd);
                float t1 = ftanh((cc[1] + bs.y) * rd);
                float t2 = ftanh((cc[2] + bs.z) * rd);
                float t3 = ftanh((cc[3] + bs.w) * rd);
                uint2 pk;
                pk.x = (unsigned int)f2b(t0) | ((unsigned int)f2b(t1) << 16);
                pk.y = (unsigned int)f2b(t2) | ((unsigned int)f2b(t3) << 16);
                *(uint2*)&cat[(size_t)(g0 + dstl) * DD + l * FD + mo * 16 + lh * 4] = pk;
            }
            // commit staged offsets for c+2 into ciL[(c+2)&1] == ciL[cur]
            if (tid < scnt) ciL[cur][tid] = sval;
            // ---- gather(c+1) into the other agg buffer ----
            if (c < NCH - 1)
                do_gather((c + 1) * CHK + gn, rs_n, re_n, eb_n, ciL[(c + 1) & 1], agg[cur ^ 1]);
            __syncthreads();
        }

        // restage hW from this layer's output (L2-hot cat)
        if (l < NL - 1) {
            #pragma unroll
            for (int i = 0; i < 8; i++) {
                int u = tid + i * 1024;
                int row = u >> 4, cu = u & 15;
                uint4 v = *(const uint4*)&cat[(size_t)(g0 + row) * DD + l * FD + cu * 8];
                *(uint4*)&hW[row * PITCH + cu * 8] = v;
            }
            __syncthreads();
        }
    }
}

// ---------------- attention scores v3: swizzled global_load_lds staging ----------------
__global__ __launch_bounds__(256) void scores_k(
    const unsigned short* __restrict__ X,   // [TN][DD] bf16
    const unsigned short* __restrict__ Wt,  // [DD][DD] bf16, (n,k)
    const float* __restrict__ bv, const float* __restrict__ vv,
    float* __restrict__ sp)                 // [TN][8] partials
{
    __shared__ unsigned short sXl[128 * 64];   // 16 KB
    __shared__ unsigned short sWl[128 * 64];   // 16 KB
    int bid = blockIdx.x;
    int swz = (bid & 7) * 512 + (bid >> 3);   // 4096 blocks, 8 XCDs
    int bx = swz >> 2, by = swz & 3;
    int tid = threadIdx.x;
    int lane = tid & 63, wid = tid >> 6;
    int wm = wid >> 1, wn = wid & 1;
    int m0 = bx * 128;
    int n0 = by * 128;
    int lr = lane & 15, lh = lane >> 4;

    f32x4 acc[4][4];
    #pragma unroll
    for (int mi = 0; mi < 4; mi++)
        #pragma unroll
        for (int ni = 0; ni < 4; ni++)
            acc[mi][ni] = (f32x4){0.f, 0.f, 0.f, 0.f};

    for (int k0 = 0; k0 < DD; k0 += 64) {
        __syncthreads();
        #pragma unroll
        for (int i = 0; i < 4; i++) {
            int u = (i << 8) + tid;
            int row = u >> 3, cu = u & 7;
            int su = cu ^ (row & 7);          // inverse-swizzled source unit
            gl_lds16(&X[(size_t)(m0 + row) * DD + k0 + su * 8], &sXl[u * 8]);
            gl_lds16(&Wt[(size_t)(n0 + row) * DD + k0 + su * 8], &sWl[u * 8]);
        }
        __syncthreads();
        #pragma unroll
        for (int kk = 0; kk < 64; kk += 32) {
            int cu0 = (kk >> 3) + lh;         // logical 16B unit 0..7
            bf16x8 afv[4], bfv[4];
            #pragma unroll
            for (int mi = 0; mi < 4; mi++) {
                int rr = wm * 64 + mi * 16 + lr;
                afv[mi] = *(const bf16x8*)&sXl[rr * 64 + ((cu0 ^ (rr & 7)) << 3)];
            }
            #pragma unroll
            for (int ni = 0; ni < 4; ni++) {
                int rr = wn * 64 + ni * 16 + lr;
                bfv[ni] = *(const bf16x8*)&sWl[rr * 64 + ((cu0 ^ (rr & 7)) << 3)];
            }
            #pragma unroll
            for (int mi = 0; mi < 4; mi++)
                #pragma unroll
                for (int ni = 0; ni < 4; ni++)
                    acc[mi][ni] = __builtin_amdgcn_mfma_f32_16x16x32_bf16(
                        afv[mi], bfv[ni], acc[mi][ni], 0, 0, 0);
        }
    }

    float vcol[4], bcol[4];
    #pragma unroll
    for (int ni = 0; ni < 4; ni++) {
        int col = n0 + wn * 64 + ni * 16 + lr;
        vcol[ni] = vv[col];
        bcol[ni] = bv[col];
    }
    #pragma unroll
    for (int mi = 0; mi < 4; mi++) {
        #pragma unroll
        for (int r = 0; r < 4; r++) {
            float part = 0.f;
            #pragma unroll
            for (int ni = 0; ni < 4; ni++)
                part += ftanh(acc[mi][ni][r] + bcol[ni]) * vcol[ni];
            part += __shfl_xor(part, 1);
            part += __shfl_xor(part, 2);
            part += __shfl_xor(part, 4);
            part += __shfl_xor(part, 8);
            if (lr == 0) {
                int row = m0 + wm * 64 + mi * 16 + lh * 4 + r;
                sp[(size_t)row * 8 + by * 2 + wn] = part;
            }
        }
    }
}

// ---------------- softmax + pool + out fused (one block per batch) ----------------
__global__ __launch_bounds__(512) void poolout_k(
    const float* __restrict__ sp, const unsigned short* __restrict__ X,
    const float* __restrict__ Wo, const float* __restrict__ bo,
    float* __restrict__ out)
{
    __shared__ float sattn[512];
    __shared__ float wmax[8];
    __shared__ float wsum[8];
    __shared__ float pred[3][512];
    __shared__ float pl[512];
    int b = blockIdx.x, t = threadIdx.x;
    int lane = t & 63, wid = t >> 6;

    float s;
    {
        const float4* p = (const float4*)&sp[((size_t)b * NN + t) * 8];
        float4 x = p[0], y = p[1];
        s = x.x + x.y + x.z + x.w + y.x + y.y + y.z + y.w;
    }
    float m = s;
    #pragma unroll
    for (int off = 1; off < 64; off <<= 1) m = fmaxf(m, __shfl_xor(m, off));
    if (lane == 0) wmax[wid] = m;
    __syncthreads();
    m = wmax[0];
    #pragma unroll
    for (int i = 1; i < 8; i++) m = fmaxf(m, wmax[i]);
    float e = expf(s - m);
    float ssum = e;
    #pragma unroll
    for (int off = 1; off < 64; off <<= 1) ssum += __shfl_xor(ssum, off);
    if (lane == 0) wsum[wid] = ssum;
    __syncthreads();
    float tot = wsum[0];
    #pragma unroll
    for (int i = 1; i < 8; i++) tot += wsum[i];
    sattn[t] = e * (1.0f / tot);
    __syncthreads();

    // pooling: 4 row-groups of 128; thread tc owns feats [4tc..4tc+3]
    int rg = t >> 7, tc = t & 127;
    float4 acc = {0.f, 0.f, 0.f, 0.f};
    const unsigned short* Xb = X + (size_t)b * NN * DD;
    int n0 = rg * 128;
    #pragma unroll 4
    for (int n = n0; n < n0 + 128; n++) {
        float a = sattn[n];
        uint2 px = *(const uint2*)&Xb[(size_t)n * DD + tc * 4];
        acc.x += a * b2f(px.x & 0xffff);
        acc.y += a * b2f(px.x >> 16);
        acc.z += a * b2f(px.y & 0xffff);
        acc.w += a * b2f(px.y >> 16);
    }
    if (rg > 0) *(float4*)&pred[rg - 1][tc * 4] = acc;
    __syncthreads();
    if (rg == 0) {
        #pragma unroll
        for (int g = 0; g < 3; g++) {
            float4 q = *(const float4*)&pred[g][tc * 4];
            acc.x += q.x; acc.y += q.y; acc.z += q.z; acc.w += q.w;
        }
        *(float4*)&pl[tc * 4] = acc;
    }
    __syncthreads();

    // output layer: 128 threads, relu(pl @ Wo + bo)
    if (t < 128) {
        float o = 0.f;
        #pragma unroll 8
        for (int k = 0; k < DD; k++) o += pl[k] * Wo[k * 128 + t];
        out[b * 128 + t] = fmaxf(o + bo[t], 0.f);
    }
}

extern "C" void kernel_launch(void* const* d_in, const int* in_sizes, int n_in,
                              void* d_out, int out_size, void* d_ws, size_t ws_size,
                              hipStream_t stream)
{
    const float* node_feat = (const float*)d_in[0];
    const int*   edge_src  = (const int*)d_in[1];
    const int*   edge_dst  = (const int*)d_in[2];
    const float* conv_W    = (const float*)d_in[3];
    const float* conv_b    = (const float*)d_in[4];
    const float* att_W     = (const float*)d_in[5];
    const float* att_b     = (const float*)d_in[6];
    const float* att_v     = (const float*)d_in[7];
    const float* out_W     = (const float*)d_in[8];
    const float* out_b     = (const float*)d_in[9];
    float* out = (float*)d_out;
    (void)in_sizes; (void)n_in; (void)out_size;

    char* ws = (char*)d_ws;
    size_t off = 0;
    auto alloc = [&](size_t bytes) {
        void* p = ws + off;
        off += (bytes + 255) & ~(size_t)255;
        return p;
    };
    unsigned short* cat   = (unsigned short*)alloc((size_t)TN * DD * 2);  // bf16
    int*   row_ptr = (int*)alloc((size_t)(TN + 1) * 4);
    int*   col_off = (int*)alloc((size_t)NE * 4);
    float* degs    = (float*)alloc((size_t)TN * 4);
    float* sp      = (float*)alloc((size_t)TN * 8 * 4);
    unsigned short* attWt = (unsigned short*)alloc((size_t)DD * DD * 2);  // bf16
    unsigned short* convWt = (unsigned short*)alloc((size_t)NL * FD * FD * 2);
    if (off > ws_size) return;  // diagnostic guard

    csr_b_k<<<NB, 1024, 0, stream>>>(edge_src, edge_dst, row_ptr, col_off, degs);
    prep_k<<<dim3(DD / 32, DD / 32, 1 + NL), 256, 0, stream>>>(att_W, conv_W, attWt, convWt);

    conv_all_k<<<NB, 1024, 0, stream>>>(node_feat, convWt, conv_b,
                                        row_ptr, col_off, degs, cat);

    scores_k<<<4096, 256, 0, stream>>>(cat, attWt, att_b, att_v, sp);
    poolout_k<<<NB, 512, 0, stream>>>(sp, cat, out_W, out_b, out);
}

// Round 19
// 350.687 us; speedup vs baseline: 1.0256x; 1.0110x over previous
//
#include <hip/hip_runtime.h>
#include <hip/hip_bf16.h>

#define TN 131072      // total nodes (B*N)
#define NB 256         // batches
#define NN 512         // nodes per batch
#define FD 128         // per-layer feature dim
#define DD 512         // concat dim
#define NE 2097152     // edges
#define NEB 8192       // edges per batch (NN*DEG)
#define NL 4           // layers
#define PITCH 136      // LDS row pitch in bf16 units (272 B)
#define CHK 32         // dst nodes per chunk (double-buffered agg)
#define NCH 16         // chunks per batch
#define CICAP 576      // staged edge-offsets per chunk (exp 512, +2.8 sigma; overflow->global tail)

typedef __attribute__((ext_vector_type(8))) short bf16x8;
typedef __attribute__((ext_vector_type(4))) float f32x4;

__device__ __forceinline__ float b2f(unsigned int u) {
    union { unsigned int i; float f; } c; c.i = u << 16; return c.f;
}
__device__ __forceinline__ unsigned short f2b(float f) {
    union { float f; unsigned int i; } c; c.f = f;
    unsigned int x = c.i;
    return (unsigned short)((x + 0x7fffu + ((x >> 16) & 1u)) >> 16);  // RNE
}
__device__ __forceinline__ void add2(float& a0, float& a1, unsigned int v) {
    union { unsigned int u; float f; } lo, hi;
    lo.u = v << 16; hi.u = v & 0xffff0000u;
    a0 += lo.f; a1 += hi.f;
}
__device__ __forceinline__ void set2(float& a0, float& a1, unsigned int v) {
    union { unsigned int u; float f; } lo, hi;
    lo.u = v << 16; hi.u = v & 0xffff0000u;
    a0 = lo.f; a1 = hi.f;
}
__device__ __forceinline__ uint4 packv8(const float* a) {
    uint4 p;
    p.x = (unsigned int)f2b(a[0]) | ((unsigned int)f2b(a[1]) << 16);
    p.y = (unsigned int)f2b(a[2]) | ((unsigned int)f2b(a[3]) << 16);
    p.z = (unsigned int)f2b(a[4]) | ((unsigned int)f2b(a[5]) << 16);
    p.w = (unsigned int)f2b(a[6]) | ((unsigned int)f2b(a[7]) << 16);
    return p;
}
// fast tanh: (e^{2x}-1)/(e^{2x}+1), clamped (bf16-exact saturation)
__device__ __forceinline__ float ftanh(float x) {
    float xc = fminf(fmaxf(x, -9.0f), 9.0f);
    float e = __expf(2.0f * xc);
    return (e - 1.0f) * __builtin_amdgcn_rcpf(e + 1.0f);
}
// async global->LDS, 16B per lane
__device__ __forceinline__ void gl_lds16(const unsigned short* g, unsigned short* l) {
    __builtin_amdgcn_global_load_lds(
        (const __attribute__((address_space(1))) unsigned int*)g,
        (__attribute__((address_space(3))) unsigned int*)l,
        16, 0, 0);
}
// acc += p.lo(bf16) * q.lo(bf16) + p.hi * q.hi  (fp32 accumulate)
__device__ __forceinline__ void dot2acc(float& acc, unsigned int p, unsigned int ones) {
    asm("v_dot2_f32_bf16 %0, %1, %2, %0" : "+v"(acc) : "v"(p), "v"(ones));
}

// ---------------- att_W transpose + bf16 cast:  Wt[n][k] = bf16(W[k][n]) ----------------
__global__ __launch_bounds__(256) void prep_k(const float* __restrict__ W,
                                              unsigned short* __restrict__ Wt) {
    __shared__ float tile[32][33];
    int k0 = blockIdx.x * 32, n0 = blockIdx.y * 32;
    int tx = threadIdx.x & 31, ty = threadIdx.x >> 5;  // 32 x 8
    #pragma unroll
    for (int i = 0; i < 32; i += 8)
        tile[ty + i][tx] = W[(size_t)(k0 + ty + i) * DD + n0 + tx];
    __syncthreads();
    #pragma unroll
    for (int i = 0; i < 32; i += 8)
        Wt[(size_t)(n0 + ty + i) * DD + k0 + tx] = f2b(tile[tx][ty + i]);
}

// ---------------- fused all-layer conv v12: in-kernel CSR + self-loaded W frags --------
// One block per batch, 1024 threads (16 waves). Prologue builds the batch CSR in
// LDS (counts/scan/cursor in agg scratch; rpL batch-relative; degs derived from
// rpL). W fragments loaded per layer from raw conv_W (L2-hot). Gather/MFMA
// pipeline identical to v10/v11 (best measured).
__global__ __launch_bounds__(1024) void conv_all_k(
    const float* __restrict__ node_feat,      // [TN][FD] fp32
    const float* __restrict__ convW,          // [NL][FD][FD] fp32 (f,o)
    const float* __restrict__ bias,           // [NL*FD]
    const int* __restrict__ src, const int* __restrict__ dst,
    int* __restrict__ col_off,                // [NE] LDS byte offsets (batch-local)
    unsigned short* __restrict__ cat)         // [TN][DD] bf16
{
    __shared__ unsigned short hW[NN * PITCH];        // 139,264 B
    __shared__ unsigned short agg[2][CHK * PITCH];   // 17,408 B (prologue: cnt/ss scratch)
    __shared__ int ciL[2][CICAP];                    // 4,608 B
    __shared__ int rpL[NN + 1];                      // 2,052 B  (total 163,332 <= 160 KiB)
    const int tid = threadIdx.x;
    const int g0 = blockIdx.x * NN;
    const int e0 = blockIdx.x * NEB;
    const int lane = tid & 63, w = tid >> 6;
    const int lr = lane & 15, lh = lane >> 4;
    const int mo = w >> 1, nd = w & 1;     // mfma: 8(out-tiles) x 2(dst-tiles)
    const int gn = tid >> 5;               // gather: node in chunk (0..31)
    const int gs = tid & 31;               // gather: 8B unit (4 feats) in row
    const char* hWb = (const char*)hW;
    const int* co = col_off + e0;          // batch-local edge offsets
    const unsigned int SEL0 = 0x01000504u; // (a.f0, b.f0)
    const unsigned int SEL1 = 0x03020706u; // (a.f1, b.f1)
    const unsigned int ONES = 0x3F803F80u; // bf16 (1.0, 1.0)

    // ---- prologue A: CSR build in LDS (cnt/ss live in agg scratch) ----
    {
        int* cnt = (int*)agg;
        int* ss  = cnt + NN;
        if (tid < NN) cnt[tid] = 0;
        __syncthreads();
        #pragma unroll
        for (int i = 0; i < NEB / 1024; i++) {
            int d = dst[e0 + tid + i * 1024] & (NN - 1);
            atomicAdd(&cnt[d], 1);
        }
        __syncthreads();
        int c = 0;
        if (tid < NN) { c = cnt[tid]; ss[tid] = c; }
        __syncthreads();
        for (int off = 1; off < NN; off <<= 1) {
            int v = (tid < NN && tid >= off) ? ss[tid - off] : 0;
            __syncthreads();
            if (tid < NN) ss[tid] += v;
            __syncthreads();
        }
        if (tid < NN) {
            int excl = ss[tid] - c;
            rpL[tid] = excl;          // batch-relative
            cnt[tid] = excl;          // cursor
        }
        if (tid == 0) rpL[NN] = NEB;
        __syncthreads();
        #pragma unroll
        for (int i = 0; i < NEB / 1024; i++) {
            int e = e0 + tid + i * 1024;
            int d = dst[e] & (NN - 1);
            int p = atomicAdd(&cnt[d], 1);
            col_off[e0 + p] = (src[e] & (NN - 1)) * (PITCH * 2);
        }
    }

    // ---- prologue B: stage node_feat fp32 -> hW bf16 ----
    #pragma unroll
    for (int i = 0; i < 8; i++) {
        int u = tid + i * 1024;
        int row = u >> 4, cu = u & 15;
        const float4* s4 = (const float4*)(node_feat + (size_t)(g0 + row) * FD + cu * 8);
        float4 x = s4[0], y = s4[1];
        float tmp[8] = {x.x, x.y, x.z, x.w, y.x, y.y, y.z, y.w};
        *(uint4*)&hW[row * PITCH + cu * 8] = packv8(tmp);
    }
    __syncthreads();   // CSR done (cnt/ss dead), hW ready, col_off visible in-block

    // gather one node's aggregation (32 lanes/node, offsets from LDS)
    auto do_gather = [&](int nl, int rs, int re, int eb, const int* cib,
                         unsigned short* buf) {
        const char* rowb = hWb + nl * (PITCH * 2);
        uint2 v = *(const uint2*)(rowb + gs * 8);
        float a0, a1, a2, a3;
        set2(a0, a1, v.x); set2(a2, a3, v.y);
        int r1 = re;
        int rlim = eb + CICAP; if (r1 > rlim) r1 = rlim;
        int j = rs;
        for (; j + 8 <= r1; j += 8) {
            int off[8];
            #pragma unroll
            for (int i = 0; i < 8; i++) off[i] = cib[j - eb + i];
            uint2 u[8];
            #pragma unroll
            for (int i = 0; i < 8; i++) u[i] = *(const uint2*)(hWb + off[i] + gs * 8);
            #pragma unroll
            for (int i = 0; i < 4; i++) {
                unsigned int x1 = u[2 * i].x, x2 = u[2 * i + 1].x;
                unsigned int y1 = u[2 * i].y, y2 = u[2 * i + 1].y;
                dot2acc(a0, __builtin_amdgcn_perm(x1, x2, SEL0), ONES);
                dot2acc(a1, __builtin_amdgcn_perm(x1, x2, SEL1), ONES);
                dot2acc(a2, __builtin_amdgcn_perm(y1, y2, SEL0), ONES);
                dot2acc(a3, __builtin_amdgcn_perm(y1, y2, SEL1), ONES);
            }
        }
        for (; j + 2 <= r1; j += 2) {
            int o0 = cib[j - eb], o1 = cib[j - eb + 1];
            uint2 u0 = *(const uint2*)(hWb + o0 + gs * 8);
            uint2 u1 = *(const uint2*)(hWb + o1 + gs * 8);
            dot2acc(a0, __builtin_amdgcn_perm(u0.x, u1.x, SEL0), ONES);
            dot2acc(a1, __builtin_amdgcn_perm(u0.x, u1.x, SEL1), ONES);
            dot2acc(a2, __builtin_amdgcn_perm(u0.y, u1.y, SEL0), ONES);
            dot2acc(a3, __builtin_amdgcn_perm(u0.y, u1.y, SEL1), ONES);
        }
        if (j < r1) {
            int off = cib[j - eb];
            uint2 u = *(const uint2*)(hWb + off + gs * 8);
            add2(a0, a1, u.x); add2(a2, a3, u.y);
            j = r1;
        }
        for (; j < re; j++) {      // rare overflow tail: offsets from global
            int off = co[j];
            uint2 u = *(const uint2*)(hWb + off + gs * 8);
            add2(a0, a1, u.x); add2(a2, a3, u.y);
        }
        uint2 pk;
        pk.x = (unsigned int)f2b(a0) | ((unsigned int)f2b(a1) << 16);
        pk.y = (unsigned int)f2b(a2) | ((unsigned int)f2b(a3) << 16);
        *(uint2*)&buf[gn * PITCH + gs * 4] = pk;
    };

    for (int l = 0; l < NL; l++) {
        // W fragments (A operand, m=out) from raw conv_W (L2-hot) + bias
        bf16x8 af[4];
        #pragma unroll
        for (int ks = 0; ks < 4; ks++) {
            const float* Wl = convW + (size_t)l * FD * FD + (size_t)(ks * 32 + lh * 8) * FD + mo * 16 + lr;
            #pragma unroll
            for (int j = 0; j < 8; j++)
                af[ks][j] = (short)f2b(Wl[(size_t)j * FD]);
        }
        float4 bs = *(const float4*)&bias[l * FD + mo * 16 + lh * 4];

        // prologue: stage ciL[0], ciL[1]; gather chunk 0
        {
            int eb0 = rpL[0];
            int cnt0 = rpL[CHK] - eb0;          if (cnt0 > CICAP) cnt0 = CICAP;
            int eb1 = rpL[CHK];
            int cnt1 = rpL[2 * CHK] - eb1;      if (cnt1 > CICAP) cnt1 = CICAP;
            int rs0 = rpL[gn], re0 = rpL[gn + 1];
            if (tid < cnt0) ciL[0][tid] = co[eb0 + tid];
            if (tid < cnt1) ciL[1][tid] = co[eb1 + tid];
            __syncthreads();
            do_gather(gn, rs0, re0, eb0, ciL[0], agg[0]);
        }
        __syncthreads();

        for (int c = 0; c < NCH; c++) {
            int cur = c & 1;
            // prefetch next-gather bounds (LDS, cheap)
            int rs_n = 0, re_n = 0, eb_n = 0;
            if (c < NCH - 1) {
                eb_n = rpL[(c + 1) * CHK];
                rs_n = rpL[(c + 1) * CHK + gn];
                re_n = rpL[(c + 1) * CHK + gn + 1];
            }
            // stage-load offsets for chunk c+2 (committed to LDS after epilogue)
            int scnt = 0, sval = 0;
            if (c <= NCH - 3) {
                int eb2 = rpL[(c + 2) * CHK];
                scnt = rpL[(c + 3) * CHK] - eb2; if (scnt > CICAP) scnt = CICAP;
                if (tid < scnt) sval = co[eb2 + tid];
            }
            // ---- MFMA(c): m=out 128, n=dst 32, k=f 128 ----
            f32x4 cc = (f32x4){0.f, 0.f, 0.f, 0.f};
            {
                const unsigned short* ab = &agg[cur][(nd * 16 + lr) * PITCH + lh * 8];
                #pragma unroll
                for (int ks = 0; ks < 4; ks++) {
                    bf16x8 bfv = *(const bf16x8*)&ab[ks * 32];
                    cc = __builtin_amdgcn_mfma_f32_16x16x32_bf16(af[ks], bfv, cc, 0, 0, 0);
                }
            }
            // ---- epilogue: tanh((lin+b)*rdeg) -> cat; deg = rpL diff + 1 ----
            {
                int dstl = c * CHK + nd * 16 + lr;
                float rd = __builtin_amdgcn_rcpf((float)(rpL[dstl + 1] - rpL[dstl] + 1));
                float t0 = ftanh((cc[0] + bs.x) * rd);
                float t1 = ftanh((cc[1] + bs.y) * rd);
                float t2 = ftanh((cc[2] + bs.z) * rd);
                float t3 = ftanh((cc[3] + bs.w) * rd);
                uint2 pk;
                pk.x = (unsigned int)f2b(t0) | ((unsigned int)f2b(t1) << 16);
                pk.y = (unsigned int)f2b(t2) | ((unsigned int)f2b(t3) << 16);
                *(uint2*)&cat[(size_t)(g0 + dstl) * DD + l * FD + mo * 16 + lh * 4] = pk;
            }
            // commit staged offsets for c+2 into ciL[(c+2)&1] == ciL[cur]
            if (tid < scnt) ciL[cur][tid] = sval;
            // ---- gather(c+1) into the other agg buffer ----
            if (c < NCH - 1)
                do_gather((c + 1) * CHK + gn, rs_n, re_n, eb_n, ciL[(c + 1) & 1], agg[cur ^ 1]);
            __syncthreads();
        }

        // restage hW from this layer's output (L2-hot cat)
        if (l < NL - 1) {
            #pragma unroll
            for (int i = 0; i < 8; i++) {
                int u = tid + i * 1024;
                int row = u >> 4, cu = u & 15;
                uint4 v = *(const uint4*)&cat[(size_t)(g0 + row) * DD + l * FD + cu * 8];
                *(uint4*)&hW[row * PITCH + cu * 8] = v;
            }
            __syncthreads();
        }
    }
}

// ---------------- attention scores v3: swizzled global_load_lds staging ----------------
__global__ __launch_bounds__(256) void scores_k(
    const unsigned short* __restrict__ X,   // [TN][DD] bf16
    const unsigned short* __restrict__ Wt,  // [DD][DD] bf16, (n,k)
    const float* __restrict__ bv, const float* __restrict__ vv,
    float* __restrict__ sp)                 // [TN][8] partials
{
    __shared__ unsigned short sXl[128 * 64];   // 16 KB
    __shared__ unsigned short sWl[128 * 64];   // 16 KB
    int bid = blockIdx.x;
    int swz = (bid & 7) * 512 + (bid >> 3);   // 4096 blocks, 8 XCDs
    int bx = swz >> 2, by = swz & 3;
    int tid = threadIdx.x;
    int lane = tid & 63, wid = tid >> 6;
    int wm = wid >> 1, wn = wid & 1;
    int m0 = bx * 128;
    int n0 = by * 128;
    int lr = lane & 15, lh = lane >> 4;

    f32x4 acc[4][4];
    #pragma unroll
    for (int mi = 0; mi < 4; mi++)
        #pragma unroll
        for (int ni = 0; ni < 4; ni++)
            acc[mi][ni] = (f32x4){0.f, 0.f, 0.f, 0.f};

    for (int k0 = 0; k0 < DD; k0 += 64) {
        __syncthreads();
        #pragma unroll
        for (int i = 0; i < 4; i++) {
            int u = (i << 8) + tid;
            int row = u >> 3, cu = u & 7;
            int su = cu ^ (row & 7);          // inverse-swizzled source unit
            gl_lds16(&X[(size_t)(m0 + row) * DD + k0 + su * 8], &sXl[u * 8]);
            gl_lds16(&Wt[(size_t)(n0 + row) * DD + k0 + su * 8], &sWl[u * 8]);
        }
        __syncthreads();
        #pragma unroll
        for (int kk = 0; kk < 64; kk += 32) {
            int cu0 = (kk >> 3) + lh;         // logical 16B unit 0..7
            bf16x8 afv[4], bfv[4];
            #pragma unroll
            for (int mi = 0; mi < 4; mi++) {
                int rr = wm * 64 + mi * 16 + lr;
                afv[mi] = *(const bf16x8*)&sXl[rr * 64 + ((cu0 ^ (rr & 7)) << 3)];
            }
            #pragma unroll
            for (int ni = 0; ni < 4; ni++) {
                int rr = wn * 64 + ni * 16 + lr;
                bfv[ni] = *(const bf16x8*)&sWl[rr * 64 + ((cu0 ^ (rr & 7)) << 3)];
            }
            #pragma unroll
            for (int mi = 0; mi < 4; mi++)
                #pragma unroll
                for (int ni = 0; ni < 4; ni++)
                    acc[mi][ni] = __builtin_amdgcn_mfma_f32_16x16x32_bf16(
                        afv[mi], bfv[ni], acc[mi][ni], 0, 0, 0);
        }
    }

    float vcol[4], bcol[4];
    #pragma unroll
    for (int ni = 0; ni < 4; ni++) {
        int col = n0 + wn * 64 + ni * 16 + lr;
        vcol[ni] = vv[col];
        bcol[ni] = bv[col];
    }
    #pragma unroll
    for (int mi = 0; mi < 4; mi++) {
        #pragma unroll
        for (int r = 0; r < 4; r++) {
            float part = 0.f;
            #pragma unroll
            for (int ni = 0; ni < 4; ni++)
                part += ftanh(acc[mi][ni][r] + bcol[ni]) * vcol[ni];
            part += __shfl_xor(part, 1);
            part += __shfl_xor(part, 2);
            part += __shfl_xor(part, 4);
            part += __shfl_xor(part, 8);
            if (lr == 0) {
                int row = m0 + wm * 64 + mi * 16 + lh * 4 + r;
                sp[(size_t)row * 8 + by * 2 + wn] = part;
            }
        }
    }
}

// ---------------- softmax + pool + out fused (one block per batch) ----------------
__global__ __launch_bounds__(512) void poolout_k(
    const float* __restrict__ sp, const unsigned short* __restrict__ X,
    const float* __restrict__ Wo, const float* __restrict__ bo,
    float* __restrict__ out)
{
    __shared__ float sattn[512];
    __shared__ float wmax[8];
    __shared__ float wsum[8];
    __shared__ float pred[3][512];
    __shared__ float pl[512];
    int b = blockIdx.x, t = threadIdx.x;
    int lane = t & 63, wid = t >> 6;

    float s;
    {
        const float4* p = (const float4*)&sp[((size_t)b * NN + t) * 8];
        float4 x = p[0], y = p[1];
        s = x.x + x.y + x.z + x.w + y.x + y.y + y.z + y.w;
    }
    float m = s;
    #pragma unroll
    for (int off = 1; off < 64; off <<= 1) m = fmaxf(m, __shfl_xor(m, off));
    if (lane == 0) wmax[wid] = m;
    __syncthreads();
    m = wmax[0];
    #pragma unroll
    for (int i = 1; i < 8; i++) m = fmaxf(m, wmax[i]);
    float e = expf(s - m);
    float ssum = e;
    #pragma unroll
    for (int off = 1; off < 64; off <<= 1) ssum += __shfl_xor(ssum, off);
    if (lane == 0) wsum[wid] = ssum;
    __syncthreads();
    float tot = wsum[0];
    #pragma unroll
    for (int i = 1; i < 8; i++) tot += wsum[i];
    sattn[t] = e * (1.0f / tot);
    __syncthreads();

    // pooling: 4 row-groups of 128; thread tc owns feats [4tc..4tc+3]
    int rg = t >> 7, tc = t & 127;
    float4 acc = {0.f, 0.f, 0.f, 0.f};
    const unsigned short* Xb = X + (size_t)b * NN * DD;
    int n0 = rg * 128;
    #pragma unroll 4
    for (int n = n0; n < n0 + 128; n++) {
        float a = sattn[n];
        uint2 px = *(const uint2*)&Xb[(size_t)n * DD + tc * 4];
        acc.x += a * b2f(px.x & 0xffff);
        acc.y += a * b2f(px.x >> 16);
        acc.z += a * b2f(px.y & 0xffff);
        acc.w += a * b2f(px.y >> 16);
    }
    if (rg > 0) *(float4*)&pred[rg - 1][tc * 4] = acc;
    __syncthreads();
    if (rg == 0) {
        #pragma unroll
        for (int g = 0; g < 3; g++) {
            float4 q = *(const float4*)&pred[g][tc * 4];
            acc.x += q.x; acc.y += q.y; acc.z += q.z; acc.w += q.w;
        }
        *(float4*)&pl[tc * 4] = acc;
    }
    __syncthreads();

    // output layer: 128 threads, relu(pl @ Wo + bo)
    if (t < 128) {
        float o = 0.f;
        #pragma unroll 8
        for (int k = 0; k < DD; k++) o += pl[k] * Wo[k * 128 + t];
        out[b * 128 + t] = fmaxf(o + bo[t], 0.f);
    }
}

extern "C" void kernel_launch(void* const* d_in, const int* in_sizes, int n_in,
                              void* d_out, int out_size, void* d_ws, size_t ws_size,
                              hipStream_t stream)
{
    const float* node_feat = (const float*)d_in[0];
    const int*   edge_src  = (const int*)d_in[1];
    const int*   edge_dst  = (const int*)d_in[2];
    const float* conv_W    = (const float*)d_in[3];
    const float* conv_b    = (const float*)d_in[4];
    const float* att_W     = (const float*)d_in[5];
    const float* att_b     = (const float*)d_in[6];
    const float* att_v     = (const float*)d_in[7];
    const float* out_W     = (const float*)d_in[8];
    const float* out_b     = (const float*)d_in[9];
    float* out = (float*)d_out;
    (void)in_sizes; (void)n_in; (void)out_size;

    char* ws = (char*)d_ws;
    size_t off = 0;
    auto alloc = [&](size_t bytes) {
        void* p = ws + off;
        off += (bytes + 255) & ~(size_t)255;
        return p;
    };
    unsigned short* cat   = (unsigned short*)alloc((size_t)TN * DD * 2);  // bf16
    int*   col_off = (int*)alloc((size_t)NE * 4);
    float* sp      = (float*)alloc((size_t)TN * 8 * 4);
    unsigned short* attWt = (unsigned short*)alloc((size_t)DD * DD * 2);  // bf16
    if (off > ws_size) return;  // diagnostic guard

    prep_k<<<dim3(DD / 32, DD / 32), 256, 0, stream>>>(att_W, attWt);

    conv_all_k<<<NB, 1024, 0, stream>>>(node_feat, conv_W, conv_b,
                                        edge_src, edge_dst, col_off, cat);

    scores_k<<<4096, 256, 0, stream>>>(cat, attWt, att_b, att_v, sp);
    poolout_k<<<NB, 512, 0, stream>>>(sp, cat, out_W, out_b, out);
}

// Round 20
// 347.642 us; speedup vs baseline: 1.0345x; 1.0088x over previous
//
#include <hip/hip_runtime.h>
#include <hip/hip_bf16.h>

#define TN 131072      // total nodes (B*N)
#define NB 256         // batches
#define NN 512         // nodes per batch
#define FD 128         // per-layer feature dim
#define DD 512         // concat dim
#define NE 2097152     // edges
#define NEB 8192       // edges per batch (NN*DEG)
#define NL 4           // layers
#define PITCH 136      // LDS row pitch in bf16 units (272 B)
#define CHK 32         // dst nodes per chunk (double-buffered agg)
#define NCH 16         // chunks per batch
#define CICAP 576      // staged edge-offsets per chunk (exp 512, +2.8 sigma; overflow->global tail)

typedef __attribute__((ext_vector_type(8))) short bf16x8;
typedef __attribute__((ext_vector_type(4))) float f32x4;

__device__ __forceinline__ float b2f(unsigned int u) {
    union { unsigned int i; float f; } c; c.i = u << 16; return c.f;
}
__device__ __forceinline__ unsigned short f2b(float f) {
    union { float f; unsigned int i; } c; c.f = f;
    unsigned int x = c.i;
    return (unsigned short)((x + 0x7fffu + ((x >> 16) & 1u)) >> 16);  // RNE
}
__device__ __forceinline__ void add2(float& a0, float& a1, unsigned int v) {
    union { unsigned int u; float f; } lo, hi;
    lo.u = v << 16; hi.u = v & 0xffff0000u;
    a0 += lo.f; a1 += hi.f;
}
__device__ __forceinline__ void set2(float& a0, float& a1, unsigned int v) {
    union { unsigned int u; float f; } lo, hi;
    lo.u = v << 16; hi.u = v & 0xffff0000u;
    a0 = lo.f; a1 = hi.f;
}
__device__ __forceinline__ uint4 packv8(const float* a) {
    uint4 p;
    p.x = (unsigned int)f2b(a[0]) | ((unsigned int)f2b(a[1]) << 16);
    p.y = (unsigned int)f2b(a[2]) | ((unsigned int)f2b(a[3]) << 16);
    p.z = (unsigned int)f2b(a[4]) | ((unsigned int)f2b(a[5]) << 16);
    p.w = (unsigned int)f2b(a[6]) | ((unsigned int)f2b(a[7]) << 16);
    return p;
}
// fast tanh: (e^{2x}-1)/(e^{2x}+1), clamped (bf16-exact saturation)
__device__ __forceinline__ float ftanh(float x) {
    float xc = fminf(fmaxf(x, -9.0f), 9.0f);
    float e = __expf(2.0f * xc);
    return (e - 1.0f) * __builtin_amdgcn_rcpf(e + 1.0f);
}
// async global->LDS, 16B per lane
__device__ __forceinline__ void gl_lds16(const unsigned short* g, unsigned short* l) {
    __builtin_amdgcn_global_load_lds(
        (const __attribute__((address_space(1))) unsigned int*)g,
        (__attribute__((address_space(3))) unsigned int*)l,
        16, 0, 0);
}
// acc += p.lo(bf16) * q.lo(bf16) + p.hi * q.hi  (fp32 accumulate)
__device__ __forceinline__ void dot2acc(float& acc, unsigned int p, unsigned int ones) {
    asm("v_dot2_f32_bf16 %0, %1, %2, %0" : "+v"(acc) : "v"(p), "v"(ones));
}

// ---------------- merged prep: attW transpose (z=0) + conv_W transpose (z=1..4) --------
__global__ __launch_bounds__(256) void prep_k(const float* __restrict__ attW,
                                              const float* __restrict__ convW,
                                              unsigned short* __restrict__ attWt,
                                              unsigned short* __restrict__ convWt) {
    __shared__ float tile[32][33];
    int z = blockIdx.z;
    int tx = threadIdx.x & 31, ty = threadIdx.x >> 5;  // 32 x 8
    if (z == 0) {
        int k0 = blockIdx.x * 32, n0 = blockIdx.y * 32;
        #pragma unroll
        for (int i = 0; i < 32; i += 8)
            tile[ty + i][tx] = attW[(size_t)(k0 + ty + i) * DD + n0 + tx];
        __syncthreads();
        #pragma unroll
        for (int i = 0; i < 32; i += 8)
            attWt[(size_t)(n0 + ty + i) * DD + k0 + tx] = f2b(tile[tx][ty + i]);
    } else {
        if (blockIdx.x >= FD / 32 || blockIdx.y >= FD / 32) return;
        const float* Wl = convW + (size_t)(z - 1) * FD * FD;
        unsigned short* Wtl = convWt + (size_t)(z - 1) * FD * FD;
        int f0 = blockIdx.x * 32, o0 = blockIdx.y * 32;
        #pragma unroll
        for (int i = 0; i < 32; i += 8)
            tile[ty + i][tx] = Wl[(size_t)(f0 + ty + i) * FD + o0 + tx];
        __syncthreads();
        #pragma unroll
        for (int i = 0; i < 32; i += 8)
            Wtl[(size_t)(o0 + ty + i) * FD + f0 + tx] = f2b(tile[tx][ty + i]);
    }
}

// ---------------- fused all-layer conv v13: in-kernel CSR + precomputed W frags --------
// One block per batch, 1024 threads (16 waves). Prologue builds the batch CSR in
// LDS (counts/scan/cursor in agg scratch; rpL batch-relative; degs from rpL diff).
// W fragments from convWt (bf16, one 16B load per ks). Gather/MFMA pipeline
// identical to v10/v11 (best measured).
__global__ __launch_bounds__(1024) void conv_all_k(
    const float* __restrict__ node_feat,      // [TN][FD] fp32
    const unsigned short* __restrict__ Wt,    // [NL*FD][FD] bf16 (out,f)
    const float* __restrict__ bias,           // [NL*FD]
    const int* __restrict__ src, const int* __restrict__ dst,
    int* __restrict__ col_off,                // [NE] LDS byte offsets (batch-local)
    unsigned short* __restrict__ cat)         // [TN][DD] bf16
{
    __shared__ unsigned short hW[NN * PITCH];        // 139,264 B
    __shared__ unsigned short agg[2][CHK * PITCH];   // 17,408 B (prologue: cnt/ss scratch)
    __shared__ int ciL[2][CICAP];                    // 4,608 B
    __shared__ int rpL[NN + 1];                      // 2,052 B  (total 163,332 <= 160 KiB)
    const int tid = threadIdx.x;
    const int g0 = blockIdx.x * NN;
    const int e0 = blockIdx.x * NEB;
    const int lane = tid & 63, w = tid >> 6;
    const int lr = lane & 15, lh = lane >> 4;
    const int mo = w >> 1, nd = w & 1;     // mfma: 8(out-tiles) x 2(dst-tiles)
    const int gn = tid >> 5;               // gather: node in chunk (0..31)
    const int gs = tid & 31;               // gather: 8B unit (4 feats) in row
    const char* hWb = (const char*)hW;
    const int* co = col_off + e0;          // batch-local edge offsets
    const unsigned int SEL0 = 0x01000504u; // (a.f0, b.f0)
    const unsigned int SEL1 = 0x03020706u; // (a.f1, b.f1)
    const unsigned int ONES = 0x3F803F80u; // bf16 (1.0, 1.0)

    // ---- prologue A: CSR build in LDS (cnt/ss live in agg scratch) ----
    {
        int* cnt = (int*)agg;
        int* ss  = cnt + NN;
        if (tid < NN) cnt[tid] = 0;
        __syncthreads();
        #pragma unroll
        for (int i = 0; i < NEB / 1024; i++) {
            int d = dst[e0 + tid + i * 1024] & (NN - 1);
            atomicAdd(&cnt[d], 1);
        }
        __syncthreads();
        int c = 0;
        if (tid < NN) { c = cnt[tid]; ss[tid] = c; }
        __syncthreads();
        for (int off = 1; off < NN; off <<= 1) {
            int v = (tid < NN && tid >= off) ? ss[tid - off] : 0;
            __syncthreads();
            if (tid < NN) ss[tid] += v;
            __syncthreads();
        }
        if (tid < NN) {
            int excl = ss[tid] - c;
            rpL[tid] = excl;          // batch-relative
            cnt[tid] = excl;          // cursor
        }
        if (tid == 0) rpL[NN] = NEB;
        __syncthreads();
        #pragma unroll
        for (int i = 0; i < NEB / 1024; i++) {
            int e = e0 + tid + i * 1024;
            int d = dst[e] & (NN - 1);
            int p = atomicAdd(&cnt[d], 1);
            col_off[e0 + p] = (src[e] & (NN - 1)) * (PITCH * 2);
        }
    }

    // ---- prologue B: stage node_feat fp32 -> hW bf16 ----
    #pragma unroll
    for (int i = 0; i < 8; i++) {
        int u = tid + i * 1024;
        int row = u >> 4, cu = u & 15;
        const float4* s4 = (const float4*)(node_feat + (size_t)(g0 + row) * FD + cu * 8);
        float4 x = s4[0], y = s4[1];
        float tmp[8] = {x.x, x.y, x.z, x.w, y.x, y.y, y.z, y.w};
        *(uint4*)&hW[row * PITCH + cu * 8] = packv8(tmp);
    }
    __syncthreads();   // CSR done (cnt/ss dead), hW ready, col_off visible in-block

    // gather one node's aggregation (32 lanes/node, offsets from LDS)
    auto do_gather = [&](int nl, int rs, int re, int eb, const int* cib,
                         unsigned short* buf) {
        const char* rowb = hWb + nl * (PITCH * 2);
        uint2 v = *(const uint2*)(rowb + gs * 8);
        float a0, a1, a2, a3;
        set2(a0, a1, v.x); set2(a2, a3, v.y);
        int r1 = re;
        int rlim = eb + CICAP; if (r1 > rlim) r1 = rlim;
        int j = rs;
        for (; j + 8 <= r1; j += 8) {
            int off[8];
            #pragma unroll
            for (int i = 0; i < 8; i++) off[i] = cib[j - eb + i];
            uint2 u[8];
            #pragma unroll
            for (int i = 0; i < 8; i++) u[i] = *(const uint2*)(hWb + off[i] + gs * 8);
            #pragma unroll
            for (int i = 0; i < 4; i++) {
                unsigned int x1 = u[2 * i].x, x2 = u[2 * i + 1].x;
                unsigned int y1 = u[2 * i].y, y2 = u[2 * i + 1].y;
                dot2acc(a0, __builtin_amdgcn_perm(x1, x2, SEL0), ONES);
                dot2acc(a1, __builtin_amdgcn_perm(x1, x2, SEL1), ONES);
                dot2acc(a2, __builtin_amdgcn_perm(y1, y2, SEL0), ONES);
                dot2acc(a3, __builtin_amdgcn_perm(y1, y2, SEL1), ONES);
            }
        }
        for (; j + 2 <= r1; j += 2) {
            int o0 = cib[j - eb], o1 = cib[j - eb + 1];
            uint2 u0 = *(const uint2*)(hWb + o0 + gs * 8);
            uint2 u1 = *(const uint2*)(hWb + o1 + gs * 8);
            dot2acc(a0, __builtin_amdgcn_perm(u0.x, u1.x, SEL0), ONES);
            dot2acc(a1, __builtin_amdgcn_perm(u0.x, u1.x, SEL1), ONES);
            dot2acc(a2, __builtin_amdgcn_perm(u0.y, u1.y, SEL0), ONES);
            dot2acc(a3, __builtin_amdgcn_perm(u0.y, u1.y, SEL1), ONES);
        }
        if (j < r1) {
            int off = cib[j - eb];
            uint2 u = *(const uint2*)(hWb + off + gs * 8);
            add2(a0, a1, u.x); add2(a2, a3, u.y);
            j = r1;
        }
        for (; j < re; j++) {      // rare overflow tail: offsets from global
            int off = co[j];
            uint2 u = *(const uint2*)(hWb + off + gs * 8);
            add2(a0, a1, u.x); add2(a2, a3, u.y);
        }
        uint2 pk;
        pk.x = (unsigned int)f2b(a0) | ((unsigned int)f2b(a1) << 16);
        pk.y = (unsigned int)f2b(a2) | ((unsigned int)f2b(a3) << 16);
        *(uint2*)&buf[gn * PITCH + gs * 4] = pk;
    };

    for (int l = 0; l < NL; l++) {
        // Wt fragments (A operand, m=out) + bias in regs for the whole layer
        bf16x8 af[4];
        #pragma unroll
        for (int ks = 0; ks < 4; ks++)
            af[ks] = *(const bf16x8*)&Wt[((size_t)l * FD + mo * 16 + lr) * FD + ks * 32 + lh * 8];
        float4 bs = *(const float4*)&bias[l * FD + mo * 16 + lh * 4];

        // prologue: stage ciL[0], ciL[1]; gather chunk 0
        {
            int eb0 = rpL[0];
            int cnt0 = rpL[CHK] - eb0;          if (cnt0 > CICAP) cnt0 = CICAP;
            int eb1 = rpL[CHK];
            int cnt1 = rpL[2 * CHK] - eb1;      if (cnt1 > CICAP) cnt1 = CICAP;
            int rs0 = rpL[gn], re0 = rpL[gn + 1];
            if (tid < cnt0) ciL[0][tid] = co[eb0 + tid];
            if (tid < cnt1) ciL[1][tid] = co[eb1 + tid];
            __syncthreads();
            do_gather(gn, rs0, re0, eb0, ciL[0], agg[0]);
        }
        __syncthreads();

        for (int c = 0; c < NCH; c++) {
            int cur = c & 1;
            // prefetch next-gather bounds (LDS, cheap)
            int rs_n = 0, re_n = 0, eb_n = 0;
            if (c < NCH - 1) {
                eb_n = rpL[(c + 1) * CHK];
                rs_n = rpL[(c + 1) * CHK + gn];
                re_n = rpL[(c + 1) * CHK + gn + 1];
            }
            // stage-load offsets for chunk c+2 (committed to LDS after epilogue)
            int scnt = 0, sval = 0;
            if (c <= NCH - 3) {
                int eb2 = rpL[(c + 2) * CHK];
                scnt = rpL[(c + 3) * CHK] - eb2; if (scnt > CICAP) scnt = CICAP;
                if (tid < scnt) sval = co[eb2 + tid];
            }
            // ---- MFMA(c): m=out 128, n=dst 32, k=f 128 ----
            f32x4 cc = (f32x4){0.f, 0.f, 0.f, 0.f};
            {
                const unsigned short* ab = &agg[cur][(nd * 16 + lr) * PITCH + lh * 8];
                #pragma unroll
                for (int ks = 0; ks < 4; ks++) {
                    bf16x8 bfv = *(const bf16x8*)&ab[ks * 32];
                    cc = __builtin_amdgcn_mfma_f32_16x16x32_bf16(af[ks], bfv, cc, 0, 0, 0);
                }
            }
            // ---- epilogue: tanh((lin+b)*rdeg) -> cat; deg = rpL diff + 1 ----
            {
                int dstl = c * CHK + nd * 16 + lr;
                float rd = __builtin_amdgcn_rcpf((float)(rpL[dstl + 1] - rpL[dstl] + 1));
                float t0 = ftanh((cc[0] + bs.x) * rd);
                float t1 = ftanh((cc[1] + bs.y) * rd);
                float t2 = ftanh((cc[2] + bs.z) * rd);
                float t3 = ftanh((cc[3] + bs.w) * rd);
                uint2 pk;
                pk.x = (unsigned int)f2b(t0) | ((unsigned int)f2b(t1) << 16);
                pk.y = (unsigned int)f2b(t2) | ((unsigned int)f2b(t3) << 16);
                *(uint2*)&cat[(size_t)(g0 + dstl) * DD + l * FD + mo * 16 + lh * 4] = pk;
            }
            // commit staged offsets for c+2 into ciL[(c+2)&1] == ciL[cur]
            if (tid < scnt) ciL[cur][tid] = sval;
            // ---- gather(c+1) into the other agg buffer ----
            if (c < NCH - 1)
                do_gather((c + 1) * CHK + gn, rs_n, re_n, eb_n, ciL[(c + 1) & 1], agg[cur ^ 1]);
            __syncthreads();
        }

        // restage hW from this layer's output (L2-hot cat)
        if (l < NL - 1) {
            #pragma unroll
            for (int i = 0; i < 8; i++) {
                int u = tid + i * 1024;
                int row = u >> 4, cu = u & 15;
                uint4 v = *(const uint4*)&cat[(size_t)(g0 + row) * DD + l * FD + cu * 8];
                *(uint4*)&hW[row * PITCH + cu * 8] = v;
            }
            __syncthreads();
        }
    }
}

// ---------------- attention scores v3: swizzled global_load_lds staging ----------------
__global__ __launch_bounds__(256) void scores_k(
    const unsigned short* __restrict__ X,   // [TN][DD] bf16
    const unsigned short* __restrict__ Wt,  // [DD][DD] bf16, (n,k)
    const float* __restrict__ bv, const float* __restrict__ vv,
    float* __restrict__ sp)                 // [TN][8] partials
{
    __shared__ unsigned short sXl[128 * 64];   // 16 KB
    __shared__ unsigned short sWl[128 * 64];   // 16 KB
    int bid = blockIdx.x;
    int swz = (bid & 7) * 512 + (bid >> 3);   // 4096 blocks, 8 XCDs
    int bx = swz >> 2, by = swz & 3;
    int tid = threadIdx.x;
    int lane = tid & 63, wid = tid >> 6;
    int wm = wid >> 1, wn = wid & 1;
    int m0 = bx * 128;
    int n0 = by * 128;
    int lr = lane & 15, lh = lane >> 4;

    f32x4 acc[4][4];
    #pragma unroll
    for (int mi = 0; mi < 4; mi++)
        #pragma unroll
        for (int ni = 0; ni < 4; ni++)
            acc[mi][ni] = (f32x4){0.f, 0.f, 0.f, 0.f};

    for (int k0 = 0; k0 < DD; k0 += 64) {
        __syncthreads();
        #pragma unroll
        for (int i = 0; i < 4; i++) {
            int u = (i << 8) + tid;
            int row = u >> 3, cu = u & 7;
            int su = cu ^ (row & 7);          // inverse-swizzled source unit
            gl_lds16(&X[(size_t)(m0 + row) * DD + k0 + su * 8], &sXl[u * 8]);
            gl_lds16(&Wt[(size_t)(n0 + row) * DD + k0 + su * 8], &sWl[u * 8]);
        }
        __syncthreads();
        #pragma unroll
        for (int kk = 0; kk < 64; kk += 32) {
            int cu0 = (kk >> 3) + lh;         // logical 16B unit 0..7
            bf16x8 afv[4], bfv[4];
            #pragma unroll
            for (int mi = 0; mi < 4; mi++) {
                int rr = wm * 64 + mi * 16 + lr;
                afv[mi] = *(const bf16x8*)&sXl[rr * 64 + ((cu0 ^ (rr & 7)) << 3)];
            }
            #pragma unroll
            for (int ni = 0; ni < 4; ni++) {
                int rr = wn * 64 + ni * 16 + lr;
                bfv[ni] = *(const bf16x8*)&sWl[rr * 64 + ((cu0 ^ (rr & 7)) << 3)];
            }
            #pragma unroll
            for (int mi = 0; mi < 4; mi++)
                #pragma unroll
                for (int ni = 0; ni < 4; ni++)
                    acc[mi][ni] = __builtin_amdgcn_mfma_f32_16x16x32_bf16(
                        afv[mi], bfv[ni], acc[mi][ni], 0, 0, 0);
        }
    }

    float vcol[4], bcol[4];
    #pragma unroll
    for (int ni = 0; ni < 4; ni++) {
        int col = n0 + wn * 64 + ni * 16 + lr;
        vcol[ni] = vv[col];
        bcol[ni] = bv[col];
    }
    #pragma unroll
    for (int mi = 0; mi < 4; mi++) {
        #pragma unroll
        for (int r = 0; r < 4; r++) {
            float part = 0.f;
            #pragma unroll
            for (int ni = 0; ni < 4; ni++)
                part += ftanh(acc[mi][ni][r] + bcol[ni]) * vcol[ni];
            part += __shfl_xor(part, 1);
            part += __shfl_xor(part, 2);
            part += __shfl_xor(part, 4);
            part += __shfl_xor(part, 8);
            if (lr == 0) {
                int row = m0 + wm * 64 + mi * 16 + lh * 4 + r;
                sp[(size_t)row * 8 + by * 2 + wn] = part;
            }
        }
    }
}

// ---------------- softmax + pool + out fused (one block per batch) ----------------
__global__ __launch_bounds__(512) void poolout_k(
    const float* __restrict__ sp, const unsigned short* __restrict__ X,
    const float* __restrict__ Wo, const float* __restrict__ bo,
    float* __restrict__ out)
{
    __shared__ float sattn[512];
    __shared__ float wmax[8];
    __shared__ float wsum[8];
    __shared__ float pred[3][512];
    __shared__ float pl[512];
    int b = blockIdx.x, t = threadIdx.x;
    int lane = t & 63, wid = t >> 6;

    float s;
    {
        const float4* p = (const float4*)&sp[((size_t)b * NN + t) * 8];
        float4 x = p[0], y = p[1];
        s = x.x + x.y + x.z + x.w + y.x + y.y + y.z + y.w;
    }
    float m = s;
    #pragma unroll
    for (int off = 1; off < 64; off <<= 1) m = fmaxf(m, __shfl_xor(m, off));
    if (lane == 0) wmax[wid] = m;
    __syncthreads();
    m = wmax[0];
    #pragma unroll
    for (int i = 1; i < 8; i++) m = fmaxf(m, wmax[i]);
    float e = expf(s - m);
    float ssum = e;
    #pragma unroll
    for (int off = 1; off < 64; off <<= 1) ssum += __shfl_xor(ssum, off);
    if (lane == 0) wsum[wid] = ssum;
    __syncthreads();
    float tot = wsum[0];
    #pragma unroll
    for (int i = 1; i < 8; i++) tot += wsum[i];
    sattn[t] = e * (1.0f / tot);
    __syncthreads();

    // pooling: 4 row-groups of 128; thread tc owns feats [4tc..4tc+3]
    int rg = t >> 7, tc = t & 127;
    float4 acc = {0.f, 0.f, 0.f, 0.f};
    const unsigned short* Xb = X + (size_t)b * NN * DD;
    int n0 = rg * 128;
    #pragma unroll 4
    for (int n = n0; n < n0 + 128; n++) {
        float a = sattn[n];
        uint2 px = *(const uint2*)&Xb[(size_t)n * DD + tc * 4];
        acc.x += a * b2f(px.x & 0xffff);
        acc.y += a * b2f(px.x >> 16);
        acc.z += a * b2f(px.y & 0xffff);
        acc.w += a * b2f(px.y >> 16);
    }
    if (rg > 0) *(float4*)&pred[rg - 1][tc * 4] = acc;
    __syncthreads();
    if (rg == 0) {
        #pragma unroll
        for (int g = 0; g < 3; g++) {
            float4 q = *(const float4*)&pred[g][tc * 4];
            acc.x += q.x; acc.y += q.y; acc.z += q.z; acc.w += q.w;
        }
        *(float4*)&pl[tc * 4] = acc;
    }
    __syncthreads();

    // output layer: 128 threads, relu(pl @ Wo + bo)
    if (t < 128) {
        float o = 0.f;
        #pragma unroll 8
        for (int k = 0; k < DD; k++) o += pl[k] * Wo[k * 128 + t];
        out[b * 128 + t] = fmaxf(o + bo[t], 0.f);
    }
}

extern "C" void kernel_launch(void* const* d_in, const int* in_sizes, int n_in,
                              void* d_out, int out_size, void* d_ws, size_t ws_size,
                              hipStream_t stream)
{
    const float* node_feat = (const float*)d_in[0];
    const int*   edge_src  = (const int*)d_in[1];
    const int*   edge_dst  = (const int*)d_in[2];
    const float* conv_W    = (const float*)d_in[3];
    const float* conv_b    = (const float*)d_in[4];
    const float* att_W     = (const float*)d_in[5];
    const float* att_b     = (const float*)d_in[6];
    const float* att_v     = (const float*)d_in[7];
    const float* out_W     = (const float*)d_in[8];
    const float* out_b     = (const float*)d_in[9];
    float* out = (float*)d_out;
    (void)in_sizes; (void)n_in; (void)out_size;

    char* ws = (char*)d_ws;
    size_t off = 0;
    auto alloc = [&](size_t bytes) {
        void* p = ws + off;
        off += (bytes + 255) & ~(size_t)255;
        return p;
    };
    unsigned short* cat   = (unsigned short*)alloc((size_t)TN * DD * 2);  // bf16
    int*   col_off = (int*)alloc((size_t)NE * 4);
    float* sp      = (float*)alloc((size_t)TN * 8 * 4);
    unsigned short* attWt = (unsigned short*)alloc((size_t)DD * DD * 2);  // bf16
    unsigned short* convWt = (unsigned short*)alloc((size_t)NL * FD * FD * 2);
    if (off > ws_size) return;  // diagnostic guard

    prep_k<<<dim3(DD / 32, DD / 32, 1 + NL), 256, 0, stream>>>(att_W, conv_W, attWt, convWt);

    conv_all_k<<<NB, 1024, 0, stream>>>(node_feat, convWt, conv_b,
                                        edge_src, edge_dst, col_off, cat);

    scores_k<<<4096, 256, 0, stream>>>(cat, attWt, att_b, att_v, sp);
    poolout_k<<<NB, 512, 0, stream>>>(sp, cat, out_W, out_b, out);
}